// Round 1
// baseline (3690.259 us; speedup 1.0000x reference)
//
#include <hip/hip_runtime.h>
#include <math.h>

#define E_   128
#define H_   8
#define KD_  16
#define FF_  512
#define L_   6
#define N_   200
#define S_   50
#define G_   100
#define B_   128
#define P_   250          // N_ + S_
#define ROWS_ (B_*P_)     // 32000
#define CLIP_ 10.0f
#define EPS_  1e-5f
// 1/sqrt(KD)=0.25 ; 1/sqrt(E)=1/11.313708
#define RSQ_KD_ 0.25f
#define RSQ_E_  0.08838834764831845f

// ---------------------------------------------------------------------------
// Embedding: out[b,p,:] = p<N ? item[b,p,:]@emb_W+emb_b : sols[b,p-N,:]@semb_W+semb_b
// ---------------------------------------------------------------------------
__global__ void embed_kernel(const float* __restrict__ item, const float* __restrict__ sols,
                             const float* __restrict__ embW, const float* __restrict__ embB,
                             const float* __restrict__ sembW, const float* __restrict__ sembB,
                             float* __restrict__ out)
{
    int idx = blockIdx.x * blockDim.x + threadIdx.x;
    const int total = ROWS_ * E_;
    for (; idx < total; idx += gridDim.x * blockDim.x) {
        int e = idx & (E_ - 1);
        int r = idx >> 7;
        int b = r / P_, p = r % P_;
        float val;
        if (p < N_) {
            const float* it = item + ((long)b * N_ + p) * 3;
            val = it[0]*embW[e] + it[1]*embW[E_+e] + it[2]*embW[2*E_+e] + embB[e];
        } else {
            int s = p - N_;
            const float* sl = sols + ((long)b * S_ + s) * 2;
            val = sl[0]*sembW[e] + sl[1]*sembW[E_+e] + sembB[e];
        }
        out[idx] = val;
    }
}

// ---------------------------------------------------------------------------
// Generic batched GEMM: C[z] = A[z] @ B[z] (+bias) (+relu)
// A: (M,K) row-major lda=K ; B: (K,N) row-major ldb=N ; C: (M,N) ldc=N
// Tile 64x64, BK=16, 256 threads, 4x4 per thread.
// ---------------------------------------------------------------------------
template<int RELU>
__global__ __launch_bounds__(256) void gemm_kernel(
    const float* __restrict__ A, const float* __restrict__ Bm,
    const float* __restrict__ bias, float* __restrict__ C,
    int M, int N, int K, long sA, long sB, long sC)
{
    A  += (long)blockIdx.z * sA;
    Bm += (long)blockIdx.z * sB;
    C  += (long)blockIdx.z * sC;
    const int bm = blockIdx.y * 64, bn = blockIdx.x * 64;

    __shared__ float As[16][65];   // +1 pad: conflict-free col writes
    __shared__ float Bs[16][64];

    const int tid = threadIdx.x;
    const int tx = tid & 15, ty = tid >> 4;
    float acc[4][4] = {};

    for (int k0 = 0; k0 < K; k0 += 16) {
        {   // A tile: 64 rows x 16 k
            int kk = tid & 15, m0 = tid >> 4;
            #pragma unroll
            for (int i = 0; i < 4; ++i) {
                int m = m0 + i * 16;
                int gm = bm + m;
                As[kk][m] = (gm < M) ? A[(long)gm * K + k0 + kk] : 0.f;
            }
        }
        {   // B tile: 16 k x 64 n (coalesced: 64 consecutive n per row)
            int n = tid & 63, kb = tid >> 6;
            #pragma unroll
            for (int i = 0; i < 4; ++i) {
                int kk = kb + i * 4;
                int gn = bn + n;
                Bs[kk][n] = (gn < N) ? Bm[(long)(k0 + kk) * N + gn] : 0.f;
            }
        }
        __syncthreads();
        #pragma unroll
        for (int kk = 0; kk < 16; ++kk) {
            float a[4], bb[4];
            #pragma unroll
            for (int i = 0; i < 4; ++i) a[i]  = As[kk][ty*4 + i];
            #pragma unroll
            for (int j = 0; j < 4; ++j) bb[j] = Bs[kk][tx*4 + j];
            #pragma unroll
            for (int i = 0; i < 4; ++i)
                #pragma unroll
                for (int j = 0; j < 4; ++j)
                    acc[i][j] += a[i] * bb[j];
        }
        __syncthreads();
    }

    #pragma unroll
    for (int i = 0; i < 4; ++i) {
        int gm = bm + ty*4 + i;
        if (gm >= M) continue;
        float* crow = C + (long)gm * N;
        #pragma unroll
        for (int j = 0; j < 4; ++j) {
            int gn = bn + tx*4 + j;
            if (gn >= N) continue;
            float val = acc[i][j];
            if (bias) val += bias[gn];
            if (RELU) val = fmaxf(val, 0.f);
            crow[gn] = val;
        }
    }
}

// ---------------------------------------------------------------------------
// Flash-style attention, one (b,h) per block, one query per thread.
// q/k/v/o are flat (rows,E) with per-batch strides; head h uses cols [16h,16h+16).
// MODE: 0 none, 1 key mask mask[b*mstride+m], 2 qk mask mask[(b*Pq+qi)*mstride+m]
// ACC: accumulate into o
// ---------------------------------------------------------------------------
template<int MODE, int ACC>
__global__ __launch_bounds__(256) void attn_kernel(
    const float* __restrict__ q, const float* __restrict__ k, const float* __restrict__ v,
    float* __restrict__ o, const float* __restrict__ mask,
    int Pq, int Pk, long sq, long sk, long so, int mstride)
{
    __shared__ float Ks[N_ * KD_];
    __shared__ float Vs[N_ * KD_];
    const int b = blockIdx.x, h = blockIdx.y, tid = threadIdx.x;
    const int h16 = h * KD_;
    const float* kb = k + (long)b * sk + h16;
    const float* vb = v + (long)b * sk + h16;
    for (int idx = tid; idx < Pk * KD_; idx += 256) {
        int m = idx >> 4, d = idx & 15;
        Ks[idx] = kb[(long)m * E_ + d];
        Vs[idx] = vb[(long)m * E_ + d];
    }
    __syncthreads();
    if (tid >= Pq) return;
    const int qi = tid;

    const float* qp = q + (long)b * sq + (long)qi * E_ + h16;
    float qreg[16];
    {
        float4 q0 = *reinterpret_cast<const float4*>(qp);
        float4 q1 = *reinterpret_cast<const float4*>(qp + 4);
        float4 q2 = *reinterpret_cast<const float4*>(qp + 8);
        float4 q3 = *reinterpret_cast<const float4*>(qp + 12);
        qreg[0]=q0.x; qreg[1]=q0.y; qreg[2]=q0.z; qreg[3]=q0.w;
        qreg[4]=q1.x; qreg[5]=q1.y; qreg[6]=q1.z; qreg[7]=q1.w;
        qreg[8]=q2.x; qreg[9]=q2.y; qreg[10]=q2.z; qreg[11]=q2.w;
        qreg[12]=q3.x; qreg[13]=q3.y; qreg[14]=q3.z; qreg[15]=q3.w;
    }

    float mx = -INFINITY, sum = 0.f, acc[16];
    #pragma unroll
    for (int d = 0; d < 16; ++d) acc[d] = 0.f;

    const float* mrow = nullptr;
    if (MODE == 1) mrow = mask + (long)b * mstride;
    if (MODE == 2) mrow = mask + ((long)b * Pq + qi) * mstride;

    for (int m = 0; m < Pk; ++m) {
        float s = 0.f;
        #pragma unroll
        for (int d = 0; d < 16; ++d) s += qreg[d] * Ks[m*16 + d];
        s *= RSQ_KD_;
        if (MODE) s += mrow[m];
        if (s > mx) {
            float c = __expf(mx - s);
            sum *= c;
            #pragma unroll
            for (int d = 0; d < 16; ++d) acc[d] *= c;
            mx = s;
        }
        float wgt = __expf(s - mx);
        sum += wgt;
        #pragma unroll
        for (int d = 0; d < 16; ++d) acc[d] += wgt * Vs[m*16 + d];
    }
    float inv = 1.f / sum;
    float* op = o + (long)b * so + (long)qi * E_ + h16;
    #pragma unroll
    for (int d = 0; d < 16; ++d) {
        float val = acc[d] * inv;
        if (ACC) val += op[d];
        op[d] = val;
    }
}

// ---------------------------------------------------------------------------
// BatchNorm over all 32000 rows: two-pass (stats via atomics, then apply).
// Input is (x + y) elementwise.
// ---------------------------------------------------------------------------
__global__ __launch_bounds__(128) void bn_stats_kernel(
    const float* __restrict__ x, const float* __restrict__ y,
    float* __restrict__ sums, int rowsPerBlock)
{
    const int e = threadIdx.x;
    int r0 = blockIdx.x * rowsPerBlock;
    int r1 = min(r0 + rowsPerBlock, ROWS_);
    float s = 0.f, s2 = 0.f;
    for (int r = r0; r < r1; ++r) {
        float v = x[(long)r * E_ + e] + y[(long)r * E_ + e];
        s += v; s2 += v * v;
    }
    atomicAdd(&sums[e], s);
    atomicAdd(&sums[E_ + e], s2);
}

__global__ void bn_apply_kernel(
    const float* __restrict__ x, const float* __restrict__ y,
    const float* __restrict__ sums, const float* __restrict__ g,
    const float* __restrict__ bb, float* __restrict__ o)
{
    int idx = blockIdx.x * blockDim.x + threadIdx.x;
    const float invR = 1.f / (float)ROWS_;
    for (; idx < ROWS_ * E_; idx += gridDim.x * blockDim.x) {
        int e = idx & (E_ - 1);
        float m   = sums[e] * invR;
        float var = sums[E_ + e] * invR - m * m;
        float v = x[idx] + y[idx];
        o[idx] = (v - m) * rsqrtf(var + EPS_) * g[e] + bb[e];
    }
}

// ---------------------------------------------------------------------------
// Decoder helpers
// ---------------------------------------------------------------------------
__global__ __launch_bounds__(128) void graph_mean_kernel(
    const float* __restrict__ enc, float* __restrict__ graph)
{
    const int b = blockIdx.x, e = threadIdx.x;
    const float* p = enc + (long)b * P_ * E_ + e;
    float s = 0.f;
    for (int i = 0; i < P_; ++i) s += p[i * E_];
    graph[b * E_ + e] = s * (1.f / (float)P_);
}

__global__ void qdec_kernel(const float* __restrict__ qg, const float* __restrict__ cap,
                            const float* __restrict__ wcap, float* __restrict__ q)
{
    int idx = blockIdx.x * blockDim.x + threadIdx.x;
    for (; idx < B_ * G_ * E_; idx += gridDim.x * blockDim.x) {
        int e  = idx & (E_ - 1);
        int bg = idx >> 7;
        int b  = bg / G_;
        q[idx] = qg[b * E_ + e] + cap[bg] * wcap[e];
    }
}

// score[b,g,n] = dot(mh[b,g,:], shk[b,n,:]) * RSQ_E ; CLIP*tanh + ninf ; softmax over n
__global__ __launch_bounds__(256) void score_softmax_kernel(
    const float* __restrict__ mh,   // (B,G,E)
    const float* __restrict__ shk,  // (B,N,E)
    const float* __restrict__ ninf, // (B,G,N)
    float* __restrict__ outp)       // (B,G,N)
{
    const int bg = blockIdx.x;
    const int b = bg / G_;
    __shared__ float mrow[E_];
    __shared__ float red[8];
    const int tid = threadIdx.x;
    if (tid < E_) mrow[tid] = mh[(long)bg * E_ + tid];
    __syncthreads();

    const int n = tid;
    const bool act = (n < N_);
    float val = 0.f, s = -INFINITY;
    if (act) {
        const float* sp = shk + ((long)b * N_ + n) * E_;
        float dot = 0.f;
        #pragma unroll 4
        for (int e = 0; e < E_; e += 4) {
            float4 sv = *reinterpret_cast<const float4*>(sp + e);
            dot += mrow[e]*sv.x + mrow[e+1]*sv.y + mrow[e+2]*sv.z + mrow[e+3]*sv.w;
        }
        val = CLIP_ * tanhf(dot * RSQ_E_) + ninf[(long)bg * N_ + n];
        s = val;
    }
    // block max
    float m = s;
    #pragma unroll
    for (int o = 1; o < 64; o <<= 1) m = fmaxf(m, __shfl_xor(m, o));
    if ((tid & 63) == 0) red[tid >> 6] = m;
    __syncthreads();
    if (tid == 0) red[4] = fmaxf(fmaxf(red[0], red[1]), fmaxf(red[2], red[3]));
    __syncthreads();
    const float bmx = red[4];
    float w = act ? __expf(val - bmx) : 0.f;
    float ss = w;
    #pragma unroll
    for (int o = 1; o < 64; o <<= 1) ss += __shfl_xor(ss, o);
    if ((tid & 63) == 0) red[tid >> 6] = ss;
    __syncthreads();
    if (tid == 0) red[5] = red[0] + red[1] + red[2] + red[3];
    __syncthreads();
    if (act) outp[(long)bg * N_ + n] = w / red[5];
}

// ---------------------------------------------------------------------------
// Host launcher
// ---------------------------------------------------------------------------
static inline void launch_gemm(hipStream_t st, const float* A, const float* Bm,
                               const float* bias, float* C,
                               int M, int N, int K, long sA, long sB, long sC,
                               int Z, bool relu)
{
    dim3 grid((N + 63) / 64, (M + 63) / 64, Z);
    if (relu) gemm_kernel<1><<<grid, 256, 0, st>>>(A, Bm, bias, C, M, N, K, sA, sB, sC);
    else      gemm_kernel<0><<<grid, 256, 0, st>>>(A, Bm, bias, C, M, N, K, sA, sB, sC);
}

extern "C" void kernel_launch(void* const* d_in, const int* in_sizes, int n_in,
                              void* d_out, int out_size, void* d_ws, size_t ws_size,
                              hipStream_t stream)
{
    const float* item           = (const float*)d_in[0];
    const float* sols           = (const float*)d_in[1];
    const float* sols_mask      = (const float*)d_in[2];
    const float* capacity       = (const float*)d_in[3];
    const float* sols_mask_pomo = (const float*)d_in[4];
    const float* ninf_mask      = (const float*)d_in[5];
    const float* emb_W          = (const float*)d_in[6];
    const float* emb_b          = (const float*)d_in[7];
    const float* semb_W         = (const float*)d_in[8];
    const float* semb_b         = (const float*)d_in[9];
    const float* LWq            = (const float*)d_in[10];
    const float* LWk            = (const float*)d_in[11];
    const float* LWv            = (const float*)d_in[12];
    const float* Lcomb_W        = (const float*)d_in[13];
    const float* Lcomb_b        = (const float*)d_in[14];
    const float* Lcombs_W       = (const float*)d_in[15];
    const float* Lcombs_b       = (const float*)d_in[16];
    const float* Lbn1_g         = (const float*)d_in[17];
    const float* Lbn1_b         = (const float*)d_in[18];
    const float* Lff_W1         = (const float*)d_in[19];
    const float* Lff_b1         = (const float*)d_in[20];
    const float* Lff_W2         = (const float*)d_in[21];
    const float* Lff_b2         = (const float*)d_in[22];
    const float* Lbn2_g         = (const float*)d_in[23];
    const float* Lbn2_b         = (const float*)d_in[24];
    const float* dWq            = (const float*)d_in[25];
    const float* dWk            = (const float*)d_in[26];
    const float* dWv            = (const float*)d_in[27];
    const float* dcomb_W        = (const float*)d_in[28];
    const float* dcomb_b        = (const float*)d_in[29];
    const float* dWk_logit      = (const float*)d_in[30];

    // workspace layout (floats); total 40,960,256 floats = 163.9 MB
    float* w       = (float*)d_ws;
    float* buf_out = w;                  // 4,096,000  (B*P*E)
    float* buf_q   = w + 4096000;
    float* buf_k   = w + 8192000;
    float* buf_v   = w + 12288000;
    float* buf_oc  = w + 16384000;
    float* buf_mh  = w + 20480000;
    float* buf_ff1 = w + 24576000;       // 16,384,000 (B*P*FF)
    float* sums    = w + 40960000;       // 256
    // decoder aliases inside ff1 region (free after encoder)
    float* shk   = buf_ff1;              // B*N*E = 3,276,800
    float* graph = buf_ff1 + 3276800;    // B*E
    float* qg    = buf_ff1 + 3293184;    // B*E
    float* qdec  = buf_ff1 + 3309568;    // B*G*E = 1,638,400
    float* ocd   = buf_ff1 + 4947968;    // B*G*E
    float* mhd   = buf_ff1 + 6586368;    // B*G*E
    float* o1 = buf_q;    // alias: q/k/v free after attention
    float* o2 = buf_oc;   // alias: oc free after comb GEMMs

    const long SPE = (long)P_ * E_;  // 32000, per-batch row stride

    embed_kernel<<<2048, 256, 0, stream>>>(item, sols, emb_W, emb_b, semb_W, semb_b, buf_out);

    for (int i = 0; i < L_; ++i) {
        const float* Wq = LWq + (long)i * E_ * E_;
        const float* Wk = LWk + (long)i * E_ * E_;
        const float* Wv = LWv + (long)i * E_ * E_;

        launch_gemm(stream, buf_out, Wq, nullptr, buf_q, ROWS_, E_, E_, 0, 0, 0, 1, false);
        launch_gemm(stream, buf_out, Wk, nullptr, buf_k, ROWS_, E_, E_, 0, 0, 0, 1, false);
        launch_gemm(stream, buf_out, Wv, nullptr, buf_v, ROWS_, E_, E_, 0, 0, 0, 1, false);

        dim3 ag(B_, H_);
        // nn: queries [0,N), keys [0,N)
        attn_kernel<0,0><<<ag, 256, 0, stream>>>(buf_q, buf_k, buf_v, buf_oc,
                                                 nullptr, N_, N_, SPE, SPE, SPE, 0);
        // ns: queries [0,N), keys [N,P), key mask sols_mask(B,S), accumulate
        attn_kernel<1,1><<<ag, 256, 0, stream>>>(buf_q, buf_k + N_*E_, buf_v + N_*E_, buf_oc,
                                                 sols_mask, N_, S_, SPE, SPE, SPE, S_);
        // sn: queries [N,P), keys [0,N)
        attn_kernel<0,0><<<ag, 256, 0, stream>>>(buf_q + N_*E_, buf_k, buf_v, buf_oc + N_*E_,
                                                 nullptr, S_, N_, SPE, SPE, SPE, 0);

        // comb (batched over B, different weights for n-rows vs s-rows)
        launch_gemm(stream, buf_oc, Lcomb_W + (long)i*E_*E_, Lcomb_b + (long)i*E_,
                    buf_mh, N_, E_, E_, SPE, 0, SPE, B_, false);
        launch_gemm(stream, buf_oc + N_*E_, Lcombs_W + (long)i*E_*E_, Lcombs_b + (long)i*E_,
                    buf_mh + N_*E_, S_, E_, E_, SPE, 0, SPE, B_, false);

        // bn1: o1 = bn(out + mh)
        hipMemsetAsync(sums, 0, 2 * E_ * sizeof(float), stream);
        bn_stats_kernel<<<256, 128, 0, stream>>>(buf_out, buf_mh, sums, 125);
        bn_apply_kernel<<<2048, 256, 0, stream>>>(buf_out, buf_mh, sums,
                                                  Lbn1_g + i*E_, Lbn1_b + i*E_, o1);

        // ff
        launch_gemm(stream, o1, Lff_W1 + (long)i*E_*FF_, Lff_b1 + (long)i*FF_,
                    buf_ff1, ROWS_, FF_, E_, 0, 0, 0, 1, true);
        launch_gemm(stream, buf_ff1, Lff_W2 + (long)i*FF_*E_, Lff_b2 + (long)i*E_,
                    o2, ROWS_, E_, FF_, 0, 0, 0, 1, false);

        // bn2: out = bn(o1 + o2)
        hipMemsetAsync(sums, 0, 2 * E_ * sizeof(float), stream);
        bn_stats_kernel<<<256, 128, 0, stream>>>(o1, o2, sums, 125);
        bn_apply_kernel<<<2048, 256, 0, stream>>>(o1, o2, sums,
                                                  Lbn2_g + i*E_, Lbn2_b + i*E_, buf_out);
    }

    // ---------------- decoder ----------------
    graph_mean_kernel<<<B_, 128, 0, stream>>>(buf_out, graph);

    launch_gemm(stream, buf_out, dWk, nullptr, buf_k, ROWS_, E_, E_, 0, 0, 0, 1, false);
    launch_gemm(stream, buf_out, dWv, nullptr, buf_v, ROWS_, E_, E_, 0, 0, 0, 1, false);
    // shk = encoded[:, :N] @ dWk_logit  (batched, strided rows)
    launch_gemm(stream, buf_out, dWk_logit, nullptr, shk, N_, E_, E_, SPE, 0, (long)N_*E_, B_, false);
    // qg = graph @ dWq[:128]
    launch_gemm(stream, graph, dWq, nullptr, qg, B_, E_, E_, 0, 0, 0, 1, false);
    qdec_kernel<<<2048, 256, 0, stream>>>(qg, capacity, dWq + 128*E_, qdec);

    dim3 ag(B_, H_);
    attn_kernel<2,0><<<ag, 256, 0, stream>>>(qdec, buf_k, buf_v, ocd,
                                             ninf_mask, G_, N_, (long)G_*E_, SPE, (long)G_*E_, N_);
    attn_kernel<2,1><<<ag, 256, 0, stream>>>(qdec, buf_k + N_*E_, buf_v + N_*E_, ocd,
                                             sols_mask_pomo, G_, S_, (long)G_*E_, SPE, (long)G_*E_, S_);

    launch_gemm(stream, ocd, dcomb_W, dcomb_b, mhd, B_*G_, E_, E_, 0, 0, 0, 1, false);

    score_softmax_kernel<<<B_*G_, 256, 0, stream>>>(mhd, shk, ninf_mask, (float*)d_out);
}

// Round 2
// 3089.326 us; speedup vs baseline: 1.1945x; 1.1945x over previous
//
#include <hip/hip_runtime.h>
#include <math.h>

#define E_   128
#define H_   8
#define KD_  16
#define FF_  512
#define L_   6
#define N_   200
#define S_   50
#define G_   100
#define B_   128
#define P_   250          // N_ + S_
#define ROWS_ (B_*P_)     // 32000
#define CLIP_ 10.0f
#define EPS_  1e-5f
#define RSQ_KD_ 0.25f
#define RSQ_E_  0.08838834764831845f

// ---------------------------------------------------------------------------
// Embedding
// ---------------------------------------------------------------------------
__global__ void embed_kernel(const float* __restrict__ item, const float* __restrict__ sols,
                             const float* __restrict__ embW, const float* __restrict__ embB,
                             const float* __restrict__ sembW, const float* __restrict__ sembB,
                             float* __restrict__ out)
{
    int idx = blockIdx.x * blockDim.x + threadIdx.x;
    const int total = ROWS_ * E_;
    for (; idx < total; idx += gridDim.x * blockDim.x) {
        int e = idx & (E_ - 1);
        int r = idx >> 7;
        int b = r / P_, p = r % P_;
        float val;
        if (p < N_) {
            const float* it = item + ((long)b * N_ + p) * 3;
            val = it[0]*embW[e] + it[1]*embW[E_+e] + it[2]*embW[2*E_+e] + embB[e];
        } else {
            int s = p - N_;
            const float* sl = sols + ((long)b * S_ + s) * 2;
            val = sl[0]*sembW[e] + sl[1]*sembW[E_+e] + sembB[e];
        }
        out[idx] = val;
    }
}

// ---------------------------------------------------------------------------
// Concatenate per-layer Wq|Wk|Wv into (L, E, 384)
// ---------------------------------------------------------------------------
__global__ void prep_wcat(const float* __restrict__ Wq, const float* __restrict__ Wk,
                          const float* __restrict__ Wv, float* __restrict__ Wcat)
{
    int idx = blockIdx.x * blockDim.x + threadIdx.x;
    const int total = L_ * E_ * 384;
    if (idx >= total) return;
    int layer = idx / (E_ * 384);
    int rem   = idx % (E_ * 384);
    int e = rem / 384;
    int c = rem % 384;
    const float* src = (c < 128) ? Wq : (c < 256) ? Wk : Wv;
    Wcat[idx] = src[((long)layer * E_ + e) * E_ + (c & 127)];
}

// ---------------------------------------------------------------------------
// Tiled GEMM: C[z] = act(A[z] @ B[z] + bias)
// A: (M,K) lda=K ; B: (K,N) ldb=N (BT=0) or (N,K) ldb=K (BT=1) ; C: (M,N)
// BM x BN tile (BN=128), BK=16, 256 threads, (BM/16)x8 per thread.
// ACT: 0 none, 1 relu, 2 CLIP*tanh(v*RSQ_E)+aux[gm*N+gn]
// ---------------------------------------------------------------------------
template<int BM, int BN, int BT, int ACT>
__global__ __launch_bounds__(256) void gemm2(
    const float* __restrict__ A, const float* __restrict__ Bm,
    const float* __restrict__ bias, const float* __restrict__ aux,
    float* __restrict__ C, int M, int N, int K,
    long sA, long sB, long sC)
{
    constexpr int BK = 16;
    constexpr int MR = BM / 64;   // float4 row-chunks per thread
    constexpr int NR = BN / 64;
    A  += (long)blockIdx.z * sA;
    Bm += (long)blockIdx.z * sB;
    C  += (long)blockIdx.z * sC;
    const float* auxz = aux + (long)blockIdx.z * sC;
    const int bm = blockIdx.y * BM, bn = blockIdx.x * BN;

    __shared__ float As[BK][BM + 4];
    __shared__ float Bs[BK][BN + 4];

    const int tid = threadIdx.x;
    const int tx = tid & 15, ty = tid >> 4;

    float acc[MR*4][NR*4] = {};

    for (int k0 = 0; k0 < K; k0 += BK) {
        // ---- stage A (k-major in LDS) ----
        #pragma unroll
        for (int i = 0; i < MR; ++i) {
            int m  = (tid >> 2) + i * 64;
            int kc = (tid & 3) * 4;
            int gm = bm + m;
            float4 av = make_float4(0.f,0.f,0.f,0.f);
            if (gm < M) av = *reinterpret_cast<const float4*>(A + (long)gm * K + k0 + kc);
            As[kc+0][m] = av.x; As[kc+1][m] = av.y;
            As[kc+2][m] = av.z; As[kc+3][m] = av.w;
        }
        // ---- stage B ----
        if (!BT) {
            #pragma unroll
            for (int i = 0; i < (BK*BN)/(4*256); ++i) {
                int idx = tid + i * 256;
                int kb  = idx / (BN/4);
                int c4  = (idx % (BN/4)) * 4;
                int gn  = bn + c4;
                float4 bv = make_float4(0.f,0.f,0.f,0.f);
                if (gn + 3 < N) bv = *reinterpret_cast<const float4*>(Bm + (long)(k0+kb) * N + gn);
                *reinterpret_cast<float4*>(&Bs[kb][c4]) = bv;
            }
        } else {
            #pragma unroll
            for (int i = 0; i < BN/64; ++i) {
                int n  = (tid >> 2) + i * 64;
                int kc = (tid & 3) * 4;
                int gn = bn + n;
                float4 bv = make_float4(0.f,0.f,0.f,0.f);
                if (gn < N) bv = *reinterpret_cast<const float4*>(Bm + (long)gn * K + k0 + kc);
                Bs[kc+0][n] = bv.x; Bs[kc+1][n] = bv.y;
                Bs[kc+2][n] = bv.z; Bs[kc+3][n] = bv.w;
            }
        }
        __syncthreads();
        #pragma unroll
        for (int kk = 0; kk < BK; ++kk) {
            float a_s[MR*4], b_s[NR*4];
            #pragma unroll
            for (int mi = 0; mi < MR; ++mi) {
                float4 t = *reinterpret_cast<const float4*>(&As[kk][ty*4 + mi*64]);
                a_s[mi*4+0] = t.x; a_s[mi*4+1] = t.y; a_s[mi*4+2] = t.z; a_s[mi*4+3] = t.w;
            }
            #pragma unroll
            for (int ni = 0; ni < NR; ++ni) {
                float4 t = *reinterpret_cast<const float4*>(&Bs[kk][tx*4 + ni*64]);
                b_s[ni*4+0] = t.x; b_s[ni*4+1] = t.y; b_s[ni*4+2] = t.z; b_s[ni*4+3] = t.w;
            }
            #pragma unroll
            for (int r = 0; r < MR*4; ++r)
                #pragma unroll
                for (int c = 0; c < NR*4; ++c)
                    acc[r][c] += a_s[r] * b_s[c];
        }
        __syncthreads();
    }

    #pragma unroll
    for (int mi = 0; mi < MR; ++mi)
    #pragma unroll
    for (int i = 0; i < 4; ++i) {
        int gm = bm + mi*64 + ty*4 + i;
        if (gm >= M) continue;
        float* crow = C + (long)gm * N;
        #pragma unroll
        for (int ni = 0; ni < NR; ++ni)
        #pragma unroll
        for (int j = 0; j < 4; ++j) {
            int gn = bn + ni*64 + tx*4 + j;
            if (gn >= N) continue;
            float v = acc[mi*4+i][ni*4+j];
            if (bias) v += bias[gn];
            if (ACT == 1) v = fmaxf(v, 0.f);
            if (ACT == 2) v = CLIP_ * tanhf(v * RSQ_E_) + auxz[(long)gm * N + gn];
            crow[gn] = v;
        }
    }
}

template<int BM, int BN, int BT, int ACT>
static inline void launch_g(hipStream_t st, const float* A, const float* Bm,
                            const float* bias, const float* aux, float* C,
                            int M, int N, int K, long sA, long sB, long sC, int Z)
{
    dim3 grid((N + BN - 1)/BN, (M + BM - 1)/BM, Z);
    gemm2<BM,BN,BT,ACT><<<grid, 256, 0, st>>>(A, Bm, bias, aux, C, M, N, K, sA, sB, sC);
}

// ---------------------------------------------------------------------------
// Flash attention, one (b,h) per block, one query per thread.
// rsq/rsk: per-row strides of q and k/v (supports fused qkv buffer).
// o row stride fixed at E_.
// MODE: 0 none, 1 key mask [b,m], 2 qk mask [b,qi,m]; ACC accumulates into o.
// ---------------------------------------------------------------------------
template<int MODE, int ACC>
__global__ __launch_bounds__(256) void attn_kernel(
    const float* __restrict__ q, const float* __restrict__ k, const float* __restrict__ v,
    float* __restrict__ o, const float* __restrict__ mask,
    int Pq, int Pk, long sq, long sk, long so, int mstride, int rsq, int rsk)
{
    __shared__ float Ks[N_ * KD_];
    __shared__ float Vs[N_ * KD_];
    const int b = blockIdx.x, h = blockIdx.y, tid = threadIdx.x;
    const int h16 = h * KD_;
    const float* kb = k + (long)b * sk + h16;
    const float* vb = v + (long)b * sk + h16;
    for (int idx = tid; idx < Pk * 4; idx += 256) {
        int m = idx >> 2, c = (idx & 3) * 4;
        *reinterpret_cast<float4*>(&Ks[m*16 + c]) =
            *reinterpret_cast<const float4*>(kb + (long)m * rsk + c);
        *reinterpret_cast<float4*>(&Vs[m*16 + c]) =
            *reinterpret_cast<const float4*>(vb + (long)m * rsk + c);
    }
    __syncthreads();
    if (tid >= Pq) return;
    const int qi = tid;

    const float* qp = q + (long)b * sq + (long)qi * rsq + h16;
    float qreg[16];
    #pragma unroll
    for (int c = 0; c < 4; ++c) {
        float4 t = *reinterpret_cast<const float4*>(qp + c*4);
        qreg[c*4+0]=t.x; qreg[c*4+1]=t.y; qreg[c*4+2]=t.z; qreg[c*4+3]=t.w;
    }

    float mx = -INFINITY, sum = 0.f, acc[16];
    #pragma unroll
    for (int d = 0; d < 16; ++d) acc[d] = 0.f;

    const float* mrow = nullptr;
    if (MODE == 1) mrow = mask + (long)b * mstride;
    if (MODE == 2) mrow = mask + ((long)b * Pq + qi) * mstride;

    for (int m = 0; m < Pk; ++m) {
        float s = 0.f;
        #pragma unroll
        for (int d = 0; d < 16; ++d) s += qreg[d] * Ks[m*16 + d];
        s *= RSQ_KD_;
        if (MODE) s += mrow[m];
        if (s > mx) {
            float c = __expf(mx - s);
            sum *= c;
            #pragma unroll
            for (int d = 0; d < 16; ++d) acc[d] *= c;
            mx = s;
        }
        float wgt = __expf(s - mx);
        sum += wgt;
        #pragma unroll
        for (int d = 0; d < 16; ++d) acc[d] += wgt * Vs[m*16 + d];
    }
    float inv = 1.f / sum;
    float* op = o + (long)b * so + (long)qi * E_ + h16;
    #pragma unroll
    for (int d = 0; d < 16; ++d) {
        float val = acc[d] * inv;
        if (ACC) val += op[d];
        op[d] = val;
    }
}

// ---------------------------------------------------------------------------
// BatchNorm: stats (atomics) + apply (float4)
// ---------------------------------------------------------------------------
__global__ __launch_bounds__(256) void bn_stats_kernel(
    const float* __restrict__ x, const float* __restrict__ y, float* __restrict__ sums)
{
    const int e  = threadIdx.x & 127;
    const int rh = threadIdx.x >> 7;
    const int base = blockIdx.x * 64;
    float s = 0.f, s2 = 0.f;
    for (int r = base + rh; r < base + 64; r += 2) {
        float v = x[(long)r * E_ + e] + y[(long)r * E_ + e];
        s += v; s2 += v * v;
    }
    atomicAdd(&sums[e], s);
    atomicAdd(&sums[E_ + e], s2);
}

__global__ void bn_apply_kernel(
    const float* __restrict__ x, const float* __restrict__ y,
    const float* __restrict__ sums, const float* __restrict__ g,
    const float* __restrict__ bb, float* __restrict__ o)
{
    const float invR = 1.f / (float)ROWS_;
    const float4* x4 = (const float4*)x;
    const float4* y4 = (const float4*)y;
    const float4* s4 = (const float4*)sums;
    const float4* g4 = (const float4*)g;
    const float4* b4 = (const float4*)bb;
    float4* o4 = (float4*)o;
    int idx = blockIdx.x * blockDim.x + threadIdx.x;
    const int tot = ROWS_ * (E_/4);
    for (; idx < tot; idx += gridDim.x * blockDim.x) {
        int e4 = idx & 31;
        float4 sm = s4[e4], sq = s4[32 + e4], gg = g4[e4], bi = b4[e4];
        float4 xv = x4[idx], yv = y4[idx], ov;
        float m, var;
        m = sm.x*invR; var = sq.x*invR - m*m; ov.x = (xv.x+yv.x - m)*rsqrtf(var+EPS_)*gg.x + bi.x;
        m = sm.y*invR; var = sq.y*invR - m*m; ov.y = (xv.y+yv.y - m)*rsqrtf(var+EPS_)*gg.y + bi.y;
        m = sm.z*invR; var = sq.z*invR - m*m; ov.z = (xv.z+yv.z - m)*rsqrtf(var+EPS_)*gg.z + bi.z;
        m = sm.w*invR; var = sq.w*invR - m*m; ov.w = (xv.w+yv.w - m)*rsqrtf(var+EPS_)*gg.w + bi.w;
        o4[idx] = ov;
    }
}

// ---------------------------------------------------------------------------
// Decoder: graph mean + q projection + capacity, fused.
// ---------------------------------------------------------------------------
__global__ __launch_bounds__(128) void qdec_kernel(
    const float* __restrict__ enc, const float* __restrict__ cap,
    const float* __restrict__ dWq, float* __restrict__ q)
{
    const int b = blockIdx.x, e = threadIdx.x;
    __shared__ float gr[E_];
    float s = 0.f;
    const float* p = enc + (long)b * P_ * E_ + e;
    for (int i = 0; i < P_; ++i) s += p[i * E_];
    gr[e] = s * (1.f / (float)P_);
    __syncthreads();
    float qg = 0.f;
    #pragma unroll 8
    for (int kk = 0; kk < E_; ++kk) qg += gr[kk] * dWq[kk * E_ + e];
    const float wc = dWq[E_ * E_ + e];
    for (int g = 0; g < G_; ++g)
        q[((long)b * G_ + g) * E_ + e] = qg + cap[b * G_ + g] * wc;
}

// ---------------------------------------------------------------------------
// Row softmax over n (one 64-lane wave per row, 4 rows per block)
// ---------------------------------------------------------------------------
__global__ __launch_bounds__(256) void softmax_rows_kernel(
    const float* __restrict__ sc, float* __restrict__ outp)
{
    const int row  = blockIdx.x * 4 + (threadIdx.x >> 6);
    const int lane = threadIdx.x & 63;
    const float* sr = sc + (long)row * N_;
    float v[4];
    #pragma unroll
    for (int j = 0; j < 4; ++j) {
        int n = lane + j * 64;
        v[j] = (n < N_) ? sr[n] : -INFINITY;
    }
    float m = fmaxf(fmaxf(v[0], v[1]), fmaxf(v[2], v[3]));
    #pragma unroll
    for (int o = 1; o < 64; o <<= 1) m = fmaxf(m, __shfl_xor(m, o));
    float e[4], ss = 0.f;
    #pragma unroll
    for (int j = 0; j < 4; ++j) {
        int n = lane + j * 64;
        e[j] = (n < N_) ? __expf(v[j] - m) : 0.f;
        ss += e[j];
    }
    #pragma unroll
    for (int o = 1; o < 64; o <<= 1) ss += __shfl_xor(ss, o);
    float inv = 1.f / ss;
    #pragma unroll
    for (int j = 0; j < 4; ++j) {
        int n = lane + j * 64;
        if (n < N_) outp[(long)row * N_ + n] = e[j] * inv;
    }
}

// ---------------------------------------------------------------------------
// Host launcher
// ---------------------------------------------------------------------------
extern "C" void kernel_launch(void* const* d_in, const int* in_sizes, int n_in,
                              void* d_out, int out_size, void* d_ws, size_t ws_size,
                              hipStream_t stream)
{
    const float* item           = (const float*)d_in[0];
    const float* sols           = (const float*)d_in[1];
    const float* sols_mask      = (const float*)d_in[2];
    const float* capacity       = (const float*)d_in[3];
    const float* sols_mask_pomo = (const float*)d_in[4];
    const float* ninf_mask      = (const float*)d_in[5];
    const float* emb_W          = (const float*)d_in[6];
    const float* emb_b          = (const float*)d_in[7];
    const float* semb_W         = (const float*)d_in[8];
    const float* semb_b         = (const float*)d_in[9];
    const float* LWq            = (const float*)d_in[10];
    const float* LWk            = (const float*)d_in[11];
    const float* LWv            = (const float*)d_in[12];
    const float* Lcomb_W        = (const float*)d_in[13];
    const float* Lcomb_b        = (const float*)d_in[14];
    const float* Lcombs_W       = (const float*)d_in[15];
    const float* Lcombs_b       = (const float*)d_in[16];
    const float* Lbn1_g         = (const float*)d_in[17];
    const float* Lbn1_b         = (const float*)d_in[18];
    const float* Lff_W1         = (const float*)d_in[19];
    const float* Lff_b1         = (const float*)d_in[20];
    const float* Lff_W2         = (const float*)d_in[21];
    const float* Lff_b2         = (const float*)d_in[22];
    const float* Lbn2_g         = (const float*)d_in[23];
    const float* Lbn2_b         = (const float*)d_in[24];
    const float* dWq            = (const float*)d_in[25];
    const float* dWk            = (const float*)d_in[26];
    const float* dWv            = (const float*)d_in[27];
    const float* dcomb_W        = (const float*)d_in[28];
    const float* dcomb_b        = (const float*)d_in[29];
    const float* dWk_logit      = (const float*)d_in[30];

    // workspace layout (floats)
    float* w        = (float*)d_ws;
    float* buf_out  = w;                    //  4,096,000 (B,P,E)
    float* buf_qkv  = w + 4096000;          // 12,288,000 (B,P,384)
    float* buf_oc   = w + 16384000;         //  4,096,000
    float* buf_mh   = w + 20480000;         //  4,096,000
    float* buf_ff1  = w + 24576000;         // 16,384,000 (B,P,FF)
    float* sums     = w + 40960000;         //        256
    // Wcat lives in d_out (dead until the final softmax write): L*E*384 = 294,912 < out_size 2,560,000
    float* Wcat = (float*)d_out;
    // decoder aliases in ff1 region (free after encoder)
    float* shk      = buf_ff1;              // 3,276,800 (B,N,E)
    float* qdec     = buf_ff1 + 3300000;    // 1,638,400 (B,G,E)
    float* ocd      = buf_ff1 + 5000000;    // 1,638,400
    float* mhd      = buf_ff1 + 6700000;    // 1,638,400
    float* scoreb   = buf_ff1 + 8400000;    // 2,560,000 (B,G,N)
    float* dk       = buf_qkv;              // 4,096,000 (decoder K)
    float* dv       = buf_qkv + 4096000;    // 4,096,000 (decoder V)
    float* o1 = buf_qkv;                    // alias: qkv free after attention
    float* o2 = buf_oc;                     // alias: oc free after comb GEMMs

    const long SPE  = (long)P_ * E_;        // 32000 per-batch (stride-128 bufs)
    const long SPQ  = (long)P_ * 384;       // 96000 per-batch (qkv buf)

    prep_wcat<<<(L_*E_*384 + 255)/256, 256, 0, stream>>>(LWq, LWk, LWv, Wcat);
    embed_kernel<<<2048, 256, 0, stream>>>(item, sols, emb_W, emb_b, semb_W, semb_b, buf_out);

    for (int i = 0; i < L_; ++i) {
        // fused QKV: (32000,128)@(128,384)
        launch_g<128,128,0,0>(stream, buf_out, Wcat + (long)i*E_*384, nullptr, nullptr,
                              buf_qkv, ROWS_, 384, E_, 0, 0, 0, 1);

        const float* q = buf_qkv;
        const float* k = buf_qkv + 128;
        const float* v = buf_qkv + 256;
        dim3 ag(B_, H_);
        attn_kernel<0,0><<<ag, 256, 0, stream>>>(q, k, v, buf_oc, nullptr,
                                                 N_, N_, SPQ, SPQ, SPE, 0, 384, 384);
        attn_kernel<1,1><<<ag, 256, 0, stream>>>(q, k + (long)N_*384, v + (long)N_*384, buf_oc,
                                                 sols_mask, N_, S_, SPQ, SPQ, SPE, S_, 384, 384);
        attn_kernel<0,0><<<ag, 256, 0, stream>>>(q + (long)N_*384, k, v, buf_oc + N_*E_,
                                                 nullptr, S_, N_, SPQ, SPQ, SPE, 0, 384, 384);

        launch_g<64,128,0,0>(stream, buf_oc, Lcomb_W + (long)i*E_*E_, Lcomb_b + i*E_, nullptr,
                             buf_mh, N_, E_, E_, SPE, 0, SPE, B_);
        launch_g<64,128,0,0>(stream, buf_oc + N_*E_, Lcombs_W + (long)i*E_*E_, Lcombs_b + i*E_, nullptr,
                             buf_mh + N_*E_, S_, E_, E_, SPE, 0, SPE, B_);

        hipMemsetAsync(sums, 0, 2 * E_ * sizeof(float), stream);
        bn_stats_kernel<<<500, 256, 0, stream>>>(buf_out, buf_mh, sums);
        bn_apply_kernel<<<1024, 256, 0, stream>>>(buf_out, buf_mh, sums,
                                                  Lbn1_g + i*E_, Lbn1_b + i*E_, o1);

        launch_g<128,128,0,1>(stream, o1, Lff_W1 + (long)i*E_*FF_, Lff_b1 + (long)i*FF_, nullptr,
                              buf_ff1, ROWS_, FF_, E_, 0, 0, 0, 1);
        launch_g<64,128,0,0>(stream, buf_ff1, Lff_W2 + (long)i*FF_*E_, Lff_b2 + i*E_, nullptr,
                             o2, ROWS_, E_, FF_, 0, 0, 0, 1);

        hipMemsetAsync(sums, 0, 2 * E_ * sizeof(float), stream);
        bn_stats_kernel<<<500, 256, 0, stream>>>(o1, o2, sums);
        bn_apply_kernel<<<1024, 256, 0, stream>>>(o1, o2, sums,
                                                  Lbn2_g + i*E_, Lbn2_b + i*E_, buf_out);
    }

    // ---------------- decoder ----------------
    launch_g<64,128,0,0>(stream, buf_out, dWk, nullptr, nullptr, dk, ROWS_, E_, E_, 0, 0, 0, 1);
    launch_g<64,128,0,0>(stream, buf_out, dWv, nullptr, nullptr, dv, ROWS_, E_, E_, 0, 0, 0, 1);
    launch_g<64,128,0,0>(stream, buf_out, dWk_logit, nullptr, nullptr, shk,
                         N_, E_, E_, SPE, 0, (long)N_*E_, B_);
    qdec_kernel<<<B_, 128, 0, stream>>>(buf_out, capacity, dWq, qdec);

    dim3 ag(B_, H_);
    attn_kernel<2,0><<<ag, 256, 0, stream>>>(qdec, dk, dv, ocd, ninf_mask,
                                             G_, N_, (long)G_*E_, SPE, (long)G_*E_, N_, E_, E_);
    attn_kernel<2,1><<<ag, 256, 0, stream>>>(qdec, dk + N_*E_, dv + N_*E_, ocd, sols_mask_pomo,
                                             G_, S_, (long)G_*E_, SPE, (long)G_*E_, S_, E_, E_);

    launch_g<64,128,0,0>(stream, ocd, dcomb_W, dcomb_b, nullptr, mhd,
                         B_*G_, E_, E_, 0, 0, 0, 1);

    // score GEMM (B-transposed: shk is (N,E)), fused CLIP*tanh + ninf
    launch_g<64,128,1,2>(stream, mhd, shk, nullptr, ninf_mask, scoreb,
                         G_, N_, E_, (long)G_*E_, (long)N_*E_, (long)G_*N_, B_);
    softmax_rows_kernel<<<(B_*G_)/4, 256, 0, stream>>>(scoreb, (float*)d_out);
}

// Round 3
// 2347.932 us; speedup vs baseline: 1.5717x; 1.3158x over previous
//
#include <hip/hip_runtime.h>
#include <math.h>

#define E_   128
#define H_   8
#define KD_  16
#define FF_  512
#define L_   6
#define N_   200
#define S_   50
#define G_   100
#define B_   128
#define P_   250          // N_ + S_
#define ROWS_ (B_*P_)     // 32000
#define CLIP_ 10.0f
#define EPS_  1e-5f
#define RSQ_KD_ 0.25f
#define RSQ_E_  0.08838834764831845f

typedef __attribute__((ext_vector_type(8))) short short8;
typedef __attribute__((ext_vector_type(4))) float f32x4;

__device__ __forceinline__ ushort f2bf(float f) {
    union { float f; unsigned u; } v; v.f = f;
    unsigned u = v.u;
    return (ushort)((u + 0x7FFFu + ((u >> 16) & 1u)) >> 16);
}

// ---------------------------------------------------------------------------
// Embedding: fp32 out + bf16 copy
// ---------------------------------------------------------------------------
__global__ void embed_kernel(const float* __restrict__ item, const float* __restrict__ sols,
                             const float* __restrict__ embW, const float* __restrict__ embB,
                             const float* __restrict__ sembW, const float* __restrict__ sembB,
                             float* __restrict__ out, ushort* __restrict__ obf)
{
    int idx = blockIdx.x * blockDim.x + threadIdx.x;
    const int total = ROWS_ * E_;
    for (; idx < total; idx += gridDim.x * blockDim.x) {
        int e = idx & (E_ - 1);
        int r = idx >> 7;
        int b = r / P_, p = r % P_;
        float val;
        if (p < N_) {
            const float* it = item + ((long)b * N_ + p) * 3;
            val = it[0]*embW[e] + it[1]*embW[E_+e] + it[2]*embW[2*E_+e] + embB[e];
        } else {
            int s = p - N_;
            const float* sl = sols + ((long)b * S_ + s) * 2;
            val = sl[0]*sembW[e] + sl[1]*sembW[E_+e] + sembB[e];
        }
        out[idx] = val;
        obf[idx] = f2bf(val);
    }
}

// ---------------------------------------------------------------------------
// Weight transpose+convert: src (Z,K,N) f32 -> dst (Z,N,K) bf16
// grid (N/32, K/32, Z), 256 threads
// ---------------------------------------------------------------------------
__global__ __launch_bounds__(256) void wtrans(const float* __restrict__ src, ushort* __restrict__ dst,
                                              int K, int N, long srcZ, long dstZ)
{
    __shared__ float t[32][33];
    src += (size_t)blockIdx.z * srcZ;
    dst += (size_t)blockIdx.z * dstZ;
    const int k0 = blockIdx.y * 32, n0 = blockIdx.x * 32;
    const int tr = threadIdx.x >> 3, tc4 = (threadIdx.x & 7) * 4;
    float4 v = *reinterpret_cast<const float4*>(&src[(size_t)(k0 + tr) * N + n0 + tc4]);
    t[tr][tc4+0] = v.x; t[tr][tc4+1] = v.y; t[tr][tc4+2] = v.z; t[tr][tc4+3] = v.w;
    __syncthreads();
    ushort4 o;
    o.x = f2bf(t[tc4+0][tr]); o.y = f2bf(t[tc4+1][tr]);
    o.z = f2bf(t[tc4+2][tr]); o.w = f2bf(t[tc4+3][tr]);
    *reinterpret_cast<ushort4*>(&dst[(size_t)(n0 + tr) * K + k0 + tc4]) = o;
}

// ---------------------------------------------------------------------------
// MFMA bf16 GEMM: C[z] = act(A[z] @ Bt[z]^T + bias)
// A: (M,K) bf16 row-major ; Bt: (N,K) bf16 row-major ; C: (M,N) f32 or bf16
// 128x128 tile, BK=32, 256 threads (4 waves, each 64x64), K%32==0, N%128==0.
// ---------------------------------------------------------------------------
template<int OUTBF, int RELU>
__global__ __launch_bounds__(256) void gemm_mfma(
    const ushort* __restrict__ A, const ushort* __restrict__ Bt,
    const float* __restrict__ bias, void* __restrict__ Cv,
    int M, int N, int K, long sA, long sBt, long sC)
{
    __shared__ ushort As[128*32];
    __shared__ ushort Bs[128*32];
    A  += (size_t)blockIdx.z * sA;
    Bt += (size_t)blockIdx.z * sBt;
    const int m0 = blockIdx.y * 128, n0 = blockIdx.x * 128;
    const int tid = threadIdx.x, w = tid >> 6, l = tid & 63;
    const int wr = w >> 1, wc = w & 1;

    f32x4 acc[4][4];
    #pragma unroll
    for (int i = 0; i < 4; ++i)
        #pragma unroll
        for (int j = 0; j < 4; ++j)
            acc[i][j] = (f32x4){0.f, 0.f, 0.f, 0.f};

    // staging geometry: flat byte = i*4096 + w*1024 + l*16 -> row=flat>>6, chunk=(flat>>4)&3
    int srow[2], scg[2];
    #pragma unroll
    for (int i = 0; i < 2; ++i) {
        int flat = i*4096 + w*1024 + l*16;
        int row = flat >> 6, cl = (flat >> 4) & 3;
        srow[i] = row;
        scg[i]  = cl ^ ((row >> 1) & 3);   // swizzled global chunk
    }

    for (int k0 = 0; k0 < K; k0 += 32) {
        #pragma unroll
        for (int i = 0; i < 2; ++i) {
            int ga = m0 + srow[i]; if (ga >= M) ga = M - 1;
            const ushort* gpa = A + (size_t)ga * K + k0 + scg[i]*8;
            __builtin_amdgcn_global_load_lds((const __attribute__((address_space(1))) void*)gpa,
                (__attribute__((address_space(3))) void*)(As + i*2048 + w*512), 16, 0, 0);
            const ushort* gpb = Bt + (size_t)(n0 + srow[i]) * K + k0 + scg[i]*8;
            __builtin_amdgcn_global_load_lds((const __attribute__((address_space(1))) void*)gpb,
                (__attribute__((address_space(3))) void*)(Bs + i*2048 + w*512), 16, 0, 0);
        }
        __syncthreads();

        short8 a[4], b[4];
        #pragma unroll
        for (int mi = 0; mi < 4; ++mi) {
            int row = wr*64 + mi*16 + (l & 15);
            int ch = (l >> 4) ^ ((row >> 1) & 3);
            a[mi] = *reinterpret_cast<const short8*>(&As[row*32 + ch*8]);
        }
        #pragma unroll
        for (int ni = 0; ni < 4; ++ni) {
            int row = wc*64 + ni*16 + (l & 15);
            int ch = (l >> 4) ^ ((row >> 1) & 3);
            b[ni] = *reinterpret_cast<const short8*>(&Bs[row*32 + ch*8]);
        }
        #pragma unroll
        for (int mi = 0; mi < 4; ++mi)
            #pragma unroll
            for (int ni = 0; ni < 4; ++ni)
                acc[mi][ni] = __builtin_amdgcn_mfma_f32_16x16x32_bf16(a[mi], b[ni], acc[mi][ni], 0, 0, 0);
        __syncthreads();
    }

    float bv[4];
    #pragma unroll
    for (int ni = 0; ni < 4; ++ni)
        bv[ni] = bias ? bias[n0 + wc*64 + ni*16 + (l & 15)] : 0.f;

    float*  Cf = (float*)Cv  + (size_t)blockIdx.z * sC;
    ushort* Cb = (ushort*)Cv + (size_t)blockIdx.z * sC;
    #pragma unroll
    for (int mi = 0; mi < 4; ++mi)
        #pragma unroll
        for (int j = 0; j < 4; ++j) {
            int row = m0 + wr*64 + mi*16 + (l >> 4)*4 + j;
            if (row >= M) continue;
            #pragma unroll
            for (int ni = 0; ni < 4; ++ni) {
                int col = n0 + wc*64 + ni*16 + (l & 15);
                float v = acc[mi][ni][j] + bv[ni];
                if (RELU) v = fmaxf(v, 0.f);
                if (OUTBF) Cb[(size_t)row * N + col] = f2bf(v);
                else       Cf[(size_t)row * N + col] = v;
            }
        }
}

template<int OUTBF, int RELU>
static inline void launch_mfma(hipStream_t st, const ushort* A, const ushort* Bt, const float* bias,
                               void* C, int M, int N, int K, long sA, long sBt, long sC, int Z)
{
    dim3 g(N / 128, (M + 127) / 128, Z);
    gemm_mfma<OUTBF, RELU><<<g, 256, 0, st>>>(A, Bt, bias, C, M, N, K, sA, sBt, sC);
}

// ---------------------------------------------------------------------------
// fp32 GEMM (kept for the score path): C = CLIP*tanh((A@B^T)*RSQ_E) + aux
// A:(M,K) lda=K ; B:(N,K) ldb=K ; 64x128 tile
// ---------------------------------------------------------------------------
__global__ __launch_bounds__(256) void gemm_score(
    const float* __restrict__ A, const float* __restrict__ Bm,
    const float* __restrict__ aux, float* __restrict__ C,
    int M, int N, int K, long sA, long sB, long sC)
{
    constexpr int BM = 64, BN = 128, BK = 16;
    A  += (long)blockIdx.z * sA;
    Bm += (long)blockIdx.z * sB;
    C  += (long)blockIdx.z * sC;
    const float* auxz = aux + (long)blockIdx.z * sC;
    const int bm = blockIdx.y * BM, bn = blockIdx.x * BN;

    __shared__ float As[BK][BM + 4];
    __shared__ float Bs[BK][BN + 4];
    const int tid = threadIdx.x;
    const int tx = tid & 15, ty = tid >> 4;
    float acc[4][8] = {};

    for (int k0 = 0; k0 < K; k0 += BK) {
        {
            int m  = tid >> 2;
            int kc = (tid & 3) * 4;
            int gm = bm + m;
            float4 av = make_float4(0.f,0.f,0.f,0.f);
            if (gm < M) av = *reinterpret_cast<const float4*>(A + (long)gm * K + k0 + kc);
            As[kc+0][m] = av.x; As[kc+1][m] = av.y; As[kc+2][m] = av.z; As[kc+3][m] = av.w;
        }
        #pragma unroll
        for (int i = 0; i < 2; ++i) {
            int n  = (tid >> 2) + i * 64;
            int kc = (tid & 3) * 4;
            int gn = bn + n;
            float4 bv = make_float4(0.f,0.f,0.f,0.f);
            if (gn < N) bv = *reinterpret_cast<const float4*>(Bm + (long)gn * K + k0 + kc);
            Bs[kc+0][n] = bv.x; Bs[kc+1][n] = bv.y; Bs[kc+2][n] = bv.z; Bs[kc+3][n] = bv.w;
        }
        __syncthreads();
        #pragma unroll
        for (int kk = 0; kk < BK; ++kk) {
            float a_s[4], b_s[8];
            {
                float4 t = *reinterpret_cast<const float4*>(&As[kk][ty*4]);
                a_s[0]=t.x; a_s[1]=t.y; a_s[2]=t.z; a_s[3]=t.w;
            }
            #pragma unroll
            for (int ni = 0; ni < 2; ++ni) {
                float4 t = *reinterpret_cast<const float4*>(&Bs[kk][tx*4 + ni*64]);
                b_s[ni*4+0]=t.x; b_s[ni*4+1]=t.y; b_s[ni*4+2]=t.z; b_s[ni*4+3]=t.w;
            }
            #pragma unroll
            for (int r = 0; r < 4; ++r)
                #pragma unroll
                for (int c = 0; c < 8; ++c)
                    acc[r][c] += a_s[r] * b_s[c];
        }
        __syncthreads();
    }

    #pragma unroll
    for (int i = 0; i < 4; ++i) {
        int gm = bm + ty*4 + i;
        if (gm >= M) continue;
        float* crow = C + (long)gm * N;
        #pragma unroll
        for (int ni = 0; ni < 2; ++ni)
            #pragma unroll
            for (int j = 0; j < 4; ++j) {
                int gn = bn + ni*64 + tx*4 + j;
                if (gn >= N) continue;
                float v = acc[i][ni*4+j];
                crow[gn] = CLIP_ * tanhf(v * RSQ_E_) + auxz[(long)gm * N + gn];
            }
    }
}

// ---------------------------------------------------------------------------
// Fused two-phase flash attention (independent softmaxes summed), bf16 out.
// MODE: 0 none, 1 key mask [b,m], 2 qk mask [b,qi,m]; MODE2<0 -> single phase.
// ---------------------------------------------------------------------------
template<int MODE>
__device__ __forceinline__ float attn_phase(
    const float* __restrict__ Ks, const float* __restrict__ Vs, int Pk,
    const float* __restrict__ mrow, const float qreg[16], float acc[16])
{
    float mx = -INFINITY, sum = 0.f;
    for (int m = 0; m < Pk; ++m) {
        float s = 0.f;
        #pragma unroll
        for (int d = 0; d < 16; ++d) s += qreg[d] * Ks[m*16 + d];
        s *= RSQ_KD_;
        if (MODE) s += mrow[m];
        if (__any(s > mx + 8.f)) {          // defer-max: rare, wave-uniform
            float mn = fmaxf(mx, s);
            float c = __expf(mx - mn);
            sum *= c;
            #pragma unroll
            for (int d = 0; d < 16; ++d) acc[d] *= c;
            mx = mn;
        }
        float wgt = __expf(s - mx);
        sum += wgt;
        #pragma unroll
        for (int d = 0; d < 16; ++d) acc[d] += wgt * Vs[m*16 + d];
    }
    return sum;
}

template<int NT, int PKT, int MODE1, int MODE2>
__global__ __launch_bounds__(NT) void attn2(
    const float* __restrict__ q, int rsq, long sq, int Pq,
    const float* __restrict__ k1, const float* __restrict__ v1, int Pk1, int rs1, long sk1,
    const float* __restrict__ m1, int ms1,
    const float* __restrict__ k2, const float* __restrict__ v2, int Pk2, int rs2, long sk2,
    const float* __restrict__ m2, int ms2,
    ushort* __restrict__ o, long so)
{
    __shared__ float Ks[PKT * KD_];
    __shared__ float Vs[PKT * KD_];
    const int b = blockIdx.x, h = blockIdx.y, tid = threadIdx.x;
    const int h16 = h * KD_;

    {
        const float* kb = k1 + (long)b * sk1 + h16;
        const float* vb = v1 + (long)b * sk1 + h16;
        for (int idx = tid; idx < Pk1 * 4; idx += NT) {
            int m = idx >> 2, c = (idx & 3) * 4;
            *reinterpret_cast<float4*>(&Ks[m*16 + c]) = *reinterpret_cast<const float4*>(kb + (size_t)m * rs1 + c);
            *reinterpret_cast<float4*>(&Vs[m*16 + c]) = *reinterpret_cast<const float4*>(vb + (size_t)m * rs1 + c);
        }
    }
    if constexpr (MODE2 >= 0) {
        const float* kb = k2 + (long)b * sk2 + h16;
        const float* vb = v2 + (long)b * sk2 + h16;
        for (int idx = tid; idx < Pk2 * 4; idx += NT) {
            int m = idx >> 2, c = (idx & 3) * 4;
            *reinterpret_cast<float4*>(&Ks[(Pk1+m)*16 + c]) = *reinterpret_cast<const float4*>(kb + (size_t)m * rs2 + c);
            *reinterpret_cast<float4*>(&Vs[(Pk1+m)*16 + c]) = *reinterpret_cast<const float4*>(vb + (size_t)m * rs2 + c);
        }
    }
    __syncthreads();
    if (tid >= Pq) return;
    const int qi = tid;

    const float* qp = q + (long)b * sq + (size_t)qi * rsq + h16;
    float qreg[16];
    #pragma unroll
    for (int c = 0; c < 4; ++c) {
        float4 t = *reinterpret_cast<const float4*>(qp + c*4);
        qreg[c*4+0]=t.x; qreg[c*4+1]=t.y; qreg[c*4+2]=t.z; qreg[c*4+3]=t.w;
    }

    const float* mrow1 = nullptr;
    if (MODE1 == 1) mrow1 = m1 + (long)b * ms1;
    if (MODE1 == 2) mrow1 = m1 + ((long)b * Pq + qi) * ms1;

    float out[16];
    {
        float acc1[16];
        #pragma unroll
        for (int d = 0; d < 16; ++d) acc1[d] = 0.f;
        float sum1 = attn_phase<MODE1>(Ks, Vs, Pk1, mrow1, qreg, acc1);
        float inv1 = 1.f / sum1;
        #pragma unroll
        for (int d = 0; d < 16; ++d) out[d] = acc1[d] * inv1;
    }
    if constexpr (MODE2 >= 0) {
        const float* mrow2 = nullptr;
        if (MODE2 == 1) mrow2 = m2 + (long)b * ms2;
        if (MODE2 == 2) mrow2 = m2 + ((long)b * Pq + qi) * ms2;
        float acc2[16];
        #pragma unroll
        for (int d = 0; d < 16; ++d) acc2[d] = 0.f;
        float sum2 = attn_phase<MODE2>(Ks + Pk1*16, Vs + Pk1*16, Pk2, mrow2, qreg, acc2);
        float inv2 = 1.f / sum2;
        #pragma unroll
        for (int d = 0; d < 16; ++d) out[d] += acc2[d] * inv2;
    }

    ushort* op = o + (long)b * so + (size_t)qi * E_ + h16;
    #pragma unroll
    for (int c = 0; c < 4; ++c) {
        ushort4 u;
        u.x = f2bf(out[c*4+0]); u.y = f2bf(out[c*4+1]);
        u.z = f2bf(out[c*4+2]); u.w = f2bf(out[c*4+3]);
        *reinterpret_cast<ushort4*>(op + c*4) = u;
    }
}

// ---------------------------------------------------------------------------
// BatchNorm: stats (atomics) + apply (float4) with bf16 copy
// ---------------------------------------------------------------------------
__global__ __launch_bounds__(256) void bn_stats_kernel(
    const float* __restrict__ x, const float* __restrict__ y, float* __restrict__ sums)
{
    const int e  = threadIdx.x & 127;
    const int rh = threadIdx.x >> 7;
    const int base = blockIdx.x * 64;
    float s = 0.f, s2 = 0.f;
    for (int r = base + rh; r < base + 64; r += 2) {
        float v = x[(long)r * E_ + e] + y[(long)r * E_ + e];
        s += v; s2 += v * v;
    }
    atomicAdd(&sums[e], s);
    atomicAdd(&sums[E_ + e], s2);
}

__global__ void bn_apply_kernel(
    const float* __restrict__ x, const float* __restrict__ y,
    const float* __restrict__ sums, const float* __restrict__ g,
    const float* __restrict__ bb, float* __restrict__ o, ushort* __restrict__ obf)
{
    const float invR = 1.f / (float)ROWS_;
    const float4* x4 = (const float4*)x;
    const float4* y4 = (const float4*)y;
    const float4* s4 = (const float4*)sums;
    const float4* g4 = (const float4*)g;
    const float4* b4 = (const float4*)bb;
    float4* o4 = (float4*)o;
    int idx = blockIdx.x * blockDim.x + threadIdx.x;
    const int tot = ROWS_ * (E_/4);
    for (; idx < tot; idx += gridDim.x * blockDim.x) {
        int e4 = idx & 31;
        float4 sm = s4[e4], sq = s4[32 + e4], gg = g4[e4], bi = b4[e4];
        float4 xv = x4[idx], yv = y4[idx], ov;
        float m, var;
        m = sm.x*invR; var = sq.x*invR - m*m; ov.x = (xv.x+yv.x - m)*rsqrtf(var+EPS_)*gg.x + bi.x;
        m = sm.y*invR; var = sq.y*invR - m*m; ov.y = (xv.y+yv.y - m)*rsqrtf(var+EPS_)*gg.y + bi.y;
        m = sm.z*invR; var = sq.z*invR - m*m; ov.z = (xv.z+yv.z - m)*rsqrtf(var+EPS_)*gg.z + bi.z;
        m = sm.w*invR; var = sq.w*invR - m*m; ov.w = (xv.w+yv.w - m)*rsqrtf(var+EPS_)*gg.w + bi.w;
        o4[idx] = ov;
        ushort4 ub;
        ub.x = f2bf(ov.x); ub.y = f2bf(ov.y); ub.z = f2bf(ov.z); ub.w = f2bf(ov.w);
        *reinterpret_cast<ushort4*>(&obf[(size_t)idx * 4]) = ub;
    }
}

// ---------------------------------------------------------------------------
// Decoder: graph mean + q projection + capacity, fused. (fp32)
// ---------------------------------------------------------------------------
__global__ __launch_bounds__(128) void qdec_kernel(
    const float* __restrict__ enc, const float* __restrict__ cap,
    const float* __restrict__ dWq, float* __restrict__ q)
{
    const int b = blockIdx.x, e = threadIdx.x;
    __shared__ float gr[E_];
    float s = 0.f;
    const float* p = enc + (long)b * P_ * E_ + e;
    for (int i = 0; i < P_; ++i) s += p[i * E_];
    gr[e] = s * (1.f / (float)P_);
    __syncthreads();
    float qg = 0.f;
    #pragma unroll 8
    for (int kk = 0; kk < E_; ++kk) qg += gr[kk] * dWq[kk * E_ + e];
    const float wc = dWq[E_ * E_ + e];
    for (int g = 0; g < G_; ++g)
        q[((long)b * G_ + g) * E_ + e] = qg + cap[b * G_ + g] * wc;
}

// ---------------------------------------------------------------------------
// Row softmax over n
// ---------------------------------------------------------------------------
__global__ __launch_bounds__(256) void softmax_rows_kernel(
    const float* __restrict__ sc, float* __restrict__ outp)
{
    const int row  = blockIdx.x * 4 + (threadIdx.x >> 6);
    const int lane = threadIdx.x & 63;
    const float* sr = sc + (long)row * N_;
    float v[4];
    #pragma unroll
    for (int j = 0; j < 4; ++j) {
        int n = lane + j * 64;
        v[j] = (n < N_) ? sr[n] : -INFINITY;
    }
    float m = fmaxf(fmaxf(v[0], v[1]), fmaxf(v[2], v[3]));
    #pragma unroll
    for (int o = 1; o < 64; o <<= 1) m = fmaxf(m, __shfl_xor(m, o));
    float e[4], ss = 0.f;
    #pragma unroll
    for (int j = 0; j < 4; ++j) {
        int n = lane + j * 64;
        e[j] = (n < N_) ? __expf(v[j] - m) : 0.f;
        ss += e[j];
    }
    #pragma unroll
    for (int o = 1; o < 64; o <<= 1) ss += __shfl_xor(ss, o);
    float inv = 1.f / ss;
    #pragma unroll
    for (int j = 0; j < 4; ++j) {
        int n = lane + j * 64;
        if (n < N_) outp[(long)row * N_ + n] = e[j] * inv;
    }
}

// ---------------------------------------------------------------------------
// Host launcher
// ---------------------------------------------------------------------------
extern "C" void kernel_launch(void* const* d_in, const int* in_sizes, int n_in,
                              void* d_out, int out_size, void* d_ws, size_t ws_size,
                              hipStream_t stream)
{
    const float* item           = (const float*)d_in[0];
    const float* sols           = (const float*)d_in[1];
    const float* sols_mask      = (const float*)d_in[2];
    const float* capacity       = (const float*)d_in[3];
    const float* sols_mask_pomo = (const float*)d_in[4];
    const float* ninf_mask      = (const float*)d_in[5];
    const float* emb_W          = (const float*)d_in[6];
    const float* emb_b          = (const float*)d_in[7];
    const float* semb_W         = (const float*)d_in[8];
    const float* semb_b         = (const float*)d_in[9];
    const float* LWq            = (const float*)d_in[10];
    const float* LWk            = (const float*)d_in[11];
    const float* LWv            = (const float*)d_in[12];
    const float* Lcomb_W        = (const float*)d_in[13];
    const float* Lcomb_b        = (const float*)d_in[14];
    const float* Lcombs_W       = (const float*)d_in[15];
    const float* Lcombs_b       = (const float*)d_in[16];
    const float* Lbn1_g         = (const float*)d_in[17];
    const float* Lbn1_b         = (const float*)d_in[18];
    const float* Lff_W1         = (const float*)d_in[19];
    const float* Lff_b1         = (const float*)d_in[20];
    const float* Lff_W2         = (const float*)d_in[21];
    const float* Lff_b2         = (const float*)d_in[22];
    const float* Lbn2_g         = (const float*)d_in[23];
    const float* Lbn2_b         = (const float*)d_in[24];
    const float* dWq            = (const float*)d_in[25];
    const float* dWk            = (const float*)d_in[26];
    const float* dWv            = (const float*)d_in[27];
    const float* dcomb_W        = (const float*)d_in[28];
    const float* dcomb_b        = (const float*)d_in[29];
    const float* dWk_logit      = (const float*)d_in[30];

    float* w = (float*)d_ws;
    float*  buf_out = w;                                // (B,P,E) f32
    ushort* x_bf    = (ushort*)(w + 4096000);           // (B,P,E) bf16
    float*  qkv     = w + 6144000;                      // (B,P,384) f32
    float*  o1      = w + 6144000;                      // alias (post-attn)
    ushort* o1_bf   = (ushort*)(w + 10240000);
    float*  o2      = w + 12288000;
    float*  dkv     = w + 6144000;                      // decoder (B,P,256) f32
    ushort* oc_bf   = (ushort*)(w + 18432000);          // (B,P,E) bf16
    float*  mh      = w + 20480000;                     // (B,P,E) f32
    float*  scoreb  = w + 20480000;                     // decoder (B,G,N)
    ushort* ff1_bf  = (ushort*)(w + 24576000);          // (B,P,FF) bf16
    float*  shk     = w + 24576000;                     // decoder (B,N,E) f32
    float*  qdecb   = w + 27852800;                     // (B,G,E) f32
    ushort* ocd_bf  = (ushort*)(w + 29491200);          // (B,G,E) bf16
    float*  mhd     = w + 30310400;                     // (B,G,E) f32
    ushort* wts     = (ushort*)(w + 32768000);
    ushort* WqkvT  = wts;                // (L,384,128)
    ushort* WcombT = wts + 294912;       // (L,128,128)
    ushort* WcombsT= wts + 393216;
    ushort* Wff1T  = wts + 491520;       // (L,512,128)
    ushort* Wff2T  = wts + 884736;       // (L,128,512)
    ushort* WdkvT  = wts + 1277952;      // (256,128)
    ushort* WshkT  = wts + 1310720;      // (128,128)
    ushort* WmhdT  = wts + 1327104;      // (128,128)
    float*  sums   = w + 33440000;

    const long SPE  = (long)P_ * E_;     // 32000
    const long SPQ  = (long)P_ * 384;

    // ---- weight prep (bf16 transpose) ----
    wtrans<<<dim3(4,4,L_), 256, 0, stream>>>(LWq, WqkvT,             128, 128, 16384, 49152);
    wtrans<<<dim3(4,4,L_), 256, 0, stream>>>(LWk, WqkvT + 128*128,   128, 128, 16384, 49152);
    wtrans<<<dim3(4,4,L_), 256, 0, stream>>>(LWv, WqkvT + 256*128,   128, 128, 16384, 49152);
    wtrans<<<dim3(4,4,L_), 256, 0, stream>>>(Lcomb_W,  WcombT,       128, 128, 16384, 16384);
    wtrans<<<dim3(4,4,L_), 256, 0, stream>>>(Lcombs_W, WcombsT,      128, 128, 16384, 16384);
    wtrans<<<dim3(16,4,L_),256, 0, stream>>>(Lff_W1, Wff1T,          128, 512, 65536, 65536);
    wtrans<<<dim3(4,16,L_),256, 0, stream>>>(Lff_W2, Wff2T,          512, 128, 65536, 65536);
    wtrans<<<dim3(4,4,1),  256, 0, stream>>>(dWk, WdkvT,             128, 128, 0, 0);
    wtrans<<<dim3(4,4,1),  256, 0, stream>>>(dWv, WdkvT + 16384,     128, 128, 0, 0);
    wtrans<<<dim3(4,4,1),  256, 0, stream>>>(dWk_logit, WshkT,       128, 128, 0, 0);
    wtrans<<<dim3(4,4,1),  256, 0, stream>>>(dcomb_W, WmhdT,         128, 128, 0, 0);

    embed_kernel<<<2048, 256, 0, stream>>>(item, sols, emb_W, emb_b, semb_W, semb_b, buf_out, x_bf);

    dim3 ag(B_, H_);
    for (int i = 0; i < L_; ++i) {
        // fused QKV (MFMA): (32000,128)bf16 @ (384,128)^T -> f32
        launch_mfma<0,0>(stream, x_bf, WqkvT + (long)i*384*128, nullptr,
                         qkv, ROWS_, 384, 128, 0, 0, 0, 1);

        const float* q = qkv;
        const float* k = qkv + 128;
        const float* v = qkv + 256;
        attn2<256,250,0,1><<<ag, 256, 0, stream>>>(
            q, 384, SPQ, N_,
            k, v, N_, 384, SPQ, nullptr, 0,
            k + (long)N_*384, v + (long)N_*384, S_, 384, SPQ, sols_mask, S_,
            oc_bf, SPE);
        attn2<64,200,0,-1><<<ag, 64, 0, stream>>>(
            q + (long)N_*384, 384, SPQ, S_,
            k, v, N_, 384, SPQ, nullptr, 0,
            nullptr, nullptr, 0, 0, 0, nullptr, 0,
            oc_bf + N_*E_, SPE);

        launch_mfma<0,0>(stream, oc_bf, WcombT + (long)i*128*128, Lcomb_b + i*E_,
                         mh, N_, 128, 128, SPE, 0, SPE, B_);
        launch_mfma<0,0>(stream, oc_bf + N_*E_, WcombsT + (long)i*128*128, Lcombs_b + i*E_,
                         mh + N_*E_, S_, 128, 128, SPE, 0, SPE, B_);

        hipMemsetAsync(sums, 0, 2 * E_ * sizeof(float), stream);
        bn_stats_kernel<<<500, 256, 0, stream>>>(buf_out, mh, sums);
        bn_apply_kernel<<<1024, 256, 0, stream>>>(buf_out, mh, sums,
                                                  Lbn1_g + i*E_, Lbn1_b + i*E_, o1, o1_bf);

        launch_mfma<1,1>(stream, o1_bf, Wff1T + (long)i*512*128, Lff_b1 + (long)i*FF_,
                         ff1_bf, ROWS_, 512, 128, 0, 0, 0, 1);
        launch_mfma<0,0>(stream, ff1_bf, Wff2T + (long)i*128*512, Lff_b2 + i*E_,
                         o2, ROWS_, 128, 512, 0, 0, 0, 1);

        hipMemsetAsync(sums, 0, 2 * E_ * sizeof(float), stream);
        bn_stats_kernel<<<500, 256, 0, stream>>>(o1, o2, sums);
        bn_apply_kernel<<<1024, 256, 0, stream>>>(o1, o2, sums,
                                                  Lbn2_g + i*E_, Lbn2_b + i*E_, buf_out, x_bf);
    }

    // ---------------- decoder ----------------
    launch_mfma<0,0>(stream, x_bf, WdkvT, nullptr, dkv, ROWS_, 256, 128, 0, 0, 0, 1);
    launch_mfma<0,0>(stream, x_bf, WshkT, nullptr, shk, N_, 128, 128, SPE, 0, (long)N_*E_, B_);
    qdec_kernel<<<B_, 128, 0, stream>>>(buf_out, capacity, dWq, qdecb);

    attn2<128,250,2,2><<<ag, 128, 0, stream>>>(
        qdecb, 128, (long)G_*E_, G_,
        dkv, dkv + 128, N_, 256, (long)P_*256, ninf_mask, N_,
        dkv + (long)N_*256, dkv + 128 + (long)N_*256, S_, 256, (long)P_*256, sols_mask_pomo, S_,
        ocd_bf, (long)G_*E_);

    launch_mfma<0,0>(stream, ocd_bf, WmhdT, dcomb_b, mhd, B_*G_, 128, 128, 0, 0, 0, 1);

    // score: CLIP*tanh((mhd @ shk^T)*RSQ_E) + ninf, then row softmax
    dim3 sg(2, 2, B_);
    gemm_score<<<sg, 256, 0, stream>>>(mhd, shk, ninf_mask, scoreb,
                                       G_, N_, E_, (long)G_*E_, (long)N_*E_, (long)G_*N_);
    softmax_rows_kernel<<<(B_*G_)/4, 256, 0, stream>>>(scoreb, (float*)d_out);
}

// Round 4
// 1495.242 us; speedup vs baseline: 2.4680x; 1.5703x over previous
//
#include <hip/hip_runtime.h>
#include <math.h>

#define E_   128
#define H_   8
#define KD_  16
#define FF_  512
#define L_   6
#define N_   200
#define S_   50
#define G_   100
#define B_   128
#define P_   250          // N_ + S_
#define ROWS_ (B_*P_)     // 32000
#define CLIP_ 10.0f
#define EPS_  1e-5f
#define RSQ_KD_ 0.25f
#define RSQ_E_  0.08838834764831845f

typedef __attribute__((ext_vector_type(8))) short short8;
typedef __attribute__((ext_vector_type(4))) float f32x4;

__device__ __forceinline__ ushort f2bf(float f) {
    union { float f; unsigned u; } v; v.f = f;
    unsigned u = v.u;
    return (ushort)((u + 0x7FFFu + ((u >> 16) & 1u)) >> 16);
}

// ---------------------------------------------------------------------------
// Embedding: fp32 out + bf16 copy
// ---------------------------------------------------------------------------
__global__ void embed_kernel(const float* __restrict__ item, const float* __restrict__ sols,
                             const float* __restrict__ embW, const float* __restrict__ embB,
                             const float* __restrict__ sembW, const float* __restrict__ sembB,
                             float* __restrict__ out, ushort* __restrict__ obf)
{
    int idx = blockIdx.x * blockDim.x + threadIdx.x;
    const int total = ROWS_ * E_;
    for (; idx < total; idx += gridDim.x * blockDim.x) {
        int e = idx & (E_ - 1);
        int r = idx >> 7;
        int b = r / P_, p = r % P_;
        float val;
        if (p < N_) {
            const float* it = item + ((long)b * N_ + p) * 3;
            val = it[0]*embW[e] + it[1]*embW[E_+e] + it[2]*embW[2*E_+e] + embB[e];
        } else {
            int s = p - N_;
            const float* sl = sols + ((long)b * S_ + s) * 2;
            val = sl[0]*sembW[e] + sl[1]*sembW[E_+e] + sembB[e];
        }
        out[idx] = val;
        obf[idx] = f2bf(val);
    }
}

// ---------------------------------------------------------------------------
// Weight transpose+convert: src (Z,K,N) f32 -> dst (Z,N,K) bf16
// ---------------------------------------------------------------------------
__global__ __launch_bounds__(256) void wtrans(const float* __restrict__ src, ushort* __restrict__ dst,
                                              int K, int N, long srcZ, long dstZ)
{
    __shared__ float t[32][33];
    src += (size_t)blockIdx.z * srcZ;
    dst += (size_t)blockIdx.z * dstZ;
    const int k0 = blockIdx.y * 32, n0 = blockIdx.x * 32;
    const int tr = threadIdx.x >> 3, tc4 = (threadIdx.x & 7) * 4;
    float4 v = *reinterpret_cast<const float4*>(&src[(size_t)(k0 + tr) * N + n0 + tc4]);
    t[tr][tc4+0] = v.x; t[tr][tc4+1] = v.y; t[tr][tc4+2] = v.z; t[tr][tc4+3] = v.w;
    __syncthreads();
    ushort4 o;
    o.x = f2bf(t[tc4+0][tr]); o.y = f2bf(t[tc4+1][tr]);
    o.z = f2bf(t[tc4+2][tr]); o.w = f2bf(t[tc4+3][tr]);
    *reinterpret_cast<ushort4*>(&dst[(size_t)(n0 + tr) * K + k0 + tc4]) = o;
}

// ---------------------------------------------------------------------------
// MFMA bf16 GEMM: C[z] = act(A[z] @ Bt[z]^T + bias)  (proven R3 kernel)
// ---------------------------------------------------------------------------
template<int OUTBF, int RELU>
__global__ __launch_bounds__(256) void gemm_mfma(
    const ushort* __restrict__ A, const ushort* __restrict__ Bt,
    const float* __restrict__ bias, void* __restrict__ Cv,
    int M, int N, int K, long sA, long sBt, long sC)
{
    __shared__ ushort As[128*32];
    __shared__ ushort Bs[128*32];
    A  += (size_t)blockIdx.z * sA;
    Bt += (size_t)blockIdx.z * sBt;
    const int m0 = blockIdx.y * 128, n0 = blockIdx.x * 128;
    const int tid = threadIdx.x, w = tid >> 6, l = tid & 63;
    const int wr = w >> 1, wc = w & 1;

    f32x4 acc[4][4];
    #pragma unroll
    for (int i = 0; i < 4; ++i)
        #pragma unroll
        for (int j = 0; j < 4; ++j)
            acc[i][j] = (f32x4){0.f, 0.f, 0.f, 0.f};

    int srow[2], scg[2];
    #pragma unroll
    for (int i = 0; i < 2; ++i) {
        int flat = i*4096 + w*1024 + l*16;
        int row = flat >> 6, cl = (flat >> 4) & 3;
        srow[i] = row;
        scg[i]  = cl ^ ((row >> 1) & 3);
    }

    for (int k0 = 0; k0 < K; k0 += 32) {
        #pragma unroll
        for (int i = 0; i < 2; ++i) {
            int ga = m0 + srow[i]; if (ga >= M) ga = M - 1;
            const ushort* gpa = A + (size_t)ga * K + k0 + scg[i]*8;
            __builtin_amdgcn_global_load_lds((const __attribute__((address_space(1))) void*)gpa,
                (__attribute__((address_space(3))) void*)(As + i*2048 + w*512), 16, 0, 0);
            const ushort* gpb = Bt + (size_t)(n0 + srow[i]) * K + k0 + scg[i]*8;
            __builtin_amdgcn_global_load_lds((const __attribute__((address_space(1))) void*)gpb,
                (__attribute__((address_space(3))) void*)(Bs + i*2048 + w*512), 16, 0, 0);
        }
        __syncthreads();

        short8 a[4], b[4];
        #pragma unroll
        for (int mi = 0; mi < 4; ++mi) {
            int row = wr*64 + mi*16 + (l & 15);
            int ch = (l >> 4) ^ ((row >> 1) & 3);
            a[mi] = *reinterpret_cast<const short8*>(&As[row*32 + ch*8]);
        }
        #pragma unroll
        for (int ni = 0; ni < 4; ++ni) {
            int row = wc*64 + ni*16 + (l & 15);
            int ch = (l >> 4) ^ ((row >> 1) & 3);
            b[ni] = *reinterpret_cast<const short8*>(&Bs[row*32 + ch*8]);
        }
        #pragma unroll
        for (int mi = 0; mi < 4; ++mi)
            #pragma unroll
            for (int ni = 0; ni < 4; ++ni)
                acc[mi][ni] = __builtin_amdgcn_mfma_f32_16x16x32_bf16(a[mi], b[ni], acc[mi][ni], 0, 0, 0);
        __syncthreads();
    }

    float bv[4];
    #pragma unroll
    for (int ni = 0; ni < 4; ++ni)
        bv[ni] = bias ? bias[n0 + wc*64 + ni*16 + (l & 15)] : 0.f;

    float*  Cf = (float*)Cv  + (size_t)blockIdx.z * sC;
    ushort* Cb = (ushort*)Cv + (size_t)blockIdx.z * sC;
    #pragma unroll
    for (int mi = 0; mi < 4; ++mi)
        #pragma unroll
        for (int j = 0; j < 4; ++j) {
            int row = m0 + wr*64 + mi*16 + (l >> 4)*4 + j;
            if (row >= M) continue;
            #pragma unroll
            for (int ni = 0; ni < 4; ++ni) {
                int col = n0 + wc*64 + ni*16 + (l & 15);
                float v = acc[mi][ni][j] + bv[ni];
                if (RELU) v = fmaxf(v, 0.f);
                if (OUTBF) Cb[(size_t)row * N + col] = f2bf(v);
                else       Cf[(size_t)row * N + col] = v;
            }
        }
}

template<int OUTBF, int RELU>
static inline void launch_mfma(hipStream_t st, const ushort* A, const ushort* Bt, const float* bias,
                               void* C, int M, int N, int K, long sA, long sBt, long sC, int Z)
{
    dim3 g(N / 128, (M + 127) / 128, Z);
    gemm_mfma<OUTBF, RELU><<<g, 256, 0, st>>>(A, Bt, bias, C, M, N, K, sA, sBt, sC);
}

// ---------------------------------------------------------------------------
// MFMA fused attention. One block per (b, h, 64-query tile); 4 waves x 16 q.
// Keys laid out at cols 0..199 (seg1 = n-keys), 200..249 (seg2 = s-keys),
// 250..255 pad. Two independent softmaxes, disjoint-normalized, one PV pass.
// MODE 0 (encoder): seg2 mask = m2p[b*50 + key-200]; queries >=200 use seg1 only.
// MODE 1 (decoder): seg1 mask = m1p[(b*G+q)*200+key]; seg2 = m2p[(b*G+q)*50+key-200].
// q/kv are bf16. q col = h*16; k col = kcol0 + h*16; v col = kcol0+128+h*16.
// ---------------------------------------------------------------------------
template<int MODE>
__global__ __launch_bounds__(256) void attn_mfma(
    const ushort* __restrict__ qb, int qrs, long qbs, int Pq,
    const ushort* __restrict__ kvb, int krs, long kbs, int kcol0,
    const float* __restrict__ m1p, const float* __restrict__ m2p,
    ushort* __restrict__ out, long so)
{
    __shared__ __align__(16) char smem[5 * 8448];   // Vt + 4 per-wave P buffers
    const int b = blockIdx.x, h = blockIdx.y, q0 = blockIdx.z * 64;
    const int tid = threadIdx.x;
    const int l = tid & 63, wv = tid >> 6;
    const short8 zv = {0,0,0,0,0,0,0,0};

    // ---- stage V transposed: Vt[d 0..15][key 0..255], row stride 528 B ----
    if (tid < 128) {
        const int k0 = tid * 2;
        const int vcol = kcol0 + 128 + h * 16;
        short8 va0 = zv, va1 = zv, vb0 = zv, vb1 = zv;
        if (k0 < P_) {
            const ushort* vr = kvb + (size_t)b * kbs + (size_t)k0 * krs + vcol;
            va0 = *reinterpret_cast<const short8*>(vr);
            va1 = *reinterpret_cast<const short8*>(vr + 8);
        }
        if (k0 + 1 < P_) {
            const ushort* vr = kvb + (size_t)b * kbs + (size_t)(k0 + 1) * krs + vcol;
            vb0 = *reinterpret_cast<const short8*>(vr);
            vb1 = *reinterpret_cast<const short8*>(vr + 8);
        }
        #pragma unroll
        for (int d = 0; d < 16; ++d) {
            ushort e0 = (ushort)(d < 8 ? va0[d] : va1[d - 8]);
            ushort e1 = (ushort)(d < 8 ? vb0[d] : vb1[d - 8]);
            *reinterpret_cast<uint*>(smem + d * 528 + tid * 4) = (uint)e0 | ((uint)e1 << 16);
        }
    }
    __syncthreads();

    // ---- Q fragment (d=16 zero-padded to K=32) ----
    const int c = l >> 4;
    const int qg = q0 + wv * 16 + (l & 15);
    const int qc = (qg < Pq) ? qg : (Pq - 1);
    short8 qf = zv;
    if (c < 2) qf = *reinterpret_cast<const short8*>(
        qb + (size_t)b * qbs + (size_t)qc * qrs + h * 16 + c * 8);

    // ---- S^T = K . Q^T : lane holds col=q(l&15), rows=keys (l>>4)*4+j (+16*kt) ----
    f32x4 sacc[16];
    #pragma unroll
    for (int kt = 0; kt < 16; ++kt) sacc[kt] = (f32x4){0.f,0.f,0.f,0.f};
    const int kcol = kcol0 + h * 16;
    #pragma unroll
    for (int kt = 0; kt < 16; ++kt) {
        int kr = kt * 16 + (l & 15); if (kr > P_ - 1) kr = P_ - 1;
        short8 kf = zv;
        if (c < 2) kf = *reinterpret_cast<const short8*>(
            kvb + (size_t)b * kbs + (size_t)kr * krs + kcol + c * 8);
        sacc[kt] = __builtin_amdgcn_mfma_f32_16x16x32_bf16(kf, qf, sacc[kt], 0, 0, 0);
    }

    // ---- segmented softmax (per lane: 64 keys of its query) ----
    const int gl = c * 4;
    float m1 = -3e38f, m2 = -3e38f;
    #pragma unroll
    for (int kt = 0; kt < 16; ++kt) {
        #pragma unroll
        for (int j = 0; j < 4; ++j) {
            int key = kt * 16 + gl + j;
            float s = sacc[kt][j] * RSQ_KD_;
            if constexpr (MODE == 0) {
                if (key >= N_ && key < P_) s += m2p[b * S_ + key - N_];
            } else {
                if (key < N_)           s += m1p[((size_t)b * G_ + qc) * N_ + key];
                else if (key < P_)      s += m2p[((size_t)b * G_ + qc) * S_ + (key - N_)];
            }
            sacc[kt][j] = s;
            if (key < N_)           m1 = fmaxf(m1, s);
            else if (key < P_)      m2 = fmaxf(m2, s);
        }
    }
    m1 = fmaxf(m1, __shfl_xor(m1, 16)); m1 = fmaxf(m1, __shfl_xor(m1, 32));
    m2 = fmaxf(m2, __shfl_xor(m2, 16)); m2 = fmaxf(m2, __shfl_xor(m2, 32));

    float s1 = 0.f, s2 = 0.f;
    #pragma unroll
    for (int kt = 0; kt < 16; ++kt) {
        #pragma unroll
        for (int j = 0; j < 4; ++j) {
            int key = kt * 16 + gl + j;
            float s = sacc[kt][j], p;
            if (key < N_)      { p = __expf(s - m1); s1 += p; }
            else if (key < P_) { p = __expf(s - m2); s2 += p; }
            else               { p = 0.f; }
            sacc[kt][j] = p;
        }
    }
    s1 += __shfl_xor(s1, 16); s1 += __shfl_xor(s1, 32);
    s2 += __shfl_xor(s2, 16); s2 += __shfl_xor(s2, 32);
    const float sc1 = 1.f / s1;
    float sc2 = 1.f / s2;
    if constexpr (MODE == 0) { if (qg >= N_) sc2 = 0.f; }

    // ---- write P[q][key] bf16 into per-wave LDS (row stride 528 B) ----
    char* Pw = smem + 8448 * (1 + wv);
    #pragma unroll
    for (int kt = 0; kt < 16; ++kt) {
        float p[4];
        #pragma unroll
        for (int j = 0; j < 4; ++j) {
            int key = kt * 16 + gl + j;
            p[j] = sacc[kt][j] * (key < N_ ? sc1 : sc2);
        }
        uint u01, u23;
        asm("v_cvt_pk_bf16_f32 %0, %1, %2" : "=v"(u01) : "v"(p[0]), "v"(p[1]));
        asm("v_cvt_pk_bf16_f32 %0, %1, %2" : "=v"(u23) : "v"(p[2]), "v"(p[3]));
        *reinterpret_cast<uint*>(Pw + (l & 15) * 528 + kt * 32 + gl * 2)     = u01;
        *reinterpret_cast<uint*>(Pw + (l & 15) * 528 + kt * 32 + gl * 2 + 4) = u23;
    }

    // ---- O^T = V^T . P^T : 8 k-steps of 32 keys ----
    f32x4 oa = (f32x4){0.f,0.f,0.f,0.f};
    #pragma unroll
    for (int ks = 0; ks < 8; ++ks) {
        short8 af = *reinterpret_cast<const short8*>(smem + (l & 15) * 528 + ks * 64 + c * 16);
        short8 pf = *reinterpret_cast<const short8*>(Pw   + (l & 15) * 528 + ks * 64 + c * 16);
        oa = __builtin_amdgcn_mfma_f32_16x16x32_bf16(af, pf, oa, 0, 0, 0);
    }

    // lane: col=q (l&15), rows d = c*4+j
    if (qg < Pq) {
        ushort4 u;
        u.x = f2bf(oa[0]); u.y = f2bf(oa[1]); u.z = f2bf(oa[2]); u.w = f2bf(oa[3]);
        *reinterpret_cast<ushort4*>(out + (size_t)b * so + (size_t)qg * E_ + h * 16 + gl) = u;
    }
}

// ---------------------------------------------------------------------------
// fp32 GEMM for the score path: C = CLIP*tanh((A@B^T)*RSQ_E) + aux
// ---------------------------------------------------------------------------
__global__ __launch_bounds__(256) void gemm_score(
    const float* __restrict__ A, const float* __restrict__ Bm,
    const float* __restrict__ aux, float* __restrict__ C,
    int M, int N, int K, long sA, long sB, long sC)
{
    constexpr int BM = 64, BN = 128, BK = 16;
    A  += (long)blockIdx.z * sA;
    Bm += (long)blockIdx.z * sB;
    C  += (long)blockIdx.z * sC;
    const float* auxz = aux + (long)blockIdx.z * sC;
    const int bm = blockIdx.y * BM, bn = blockIdx.x * BN;

    __shared__ float As[BK][BM + 4];
    __shared__ float Bs[BK][BN + 4];
    const int tid = threadIdx.x;
    const int tx = tid & 15, ty = tid >> 4;
    float acc[4][8] = {};

    for (int k0 = 0; k0 < K; k0 += BK) {
        {
            int m  = tid >> 2;
            int kc = (tid & 3) * 4;
            int gm = bm + m;
            float4 av = make_float4(0.f,0.f,0.f,0.f);
            if (gm < M) av = *reinterpret_cast<const float4*>(A + (long)gm * K + k0 + kc);
            As[kc+0][m] = av.x; As[kc+1][m] = av.y; As[kc+2][m] = av.z; As[kc+3][m] = av.w;
        }
        #pragma unroll
        for (int i = 0; i < 2; ++i) {
            int n  = (tid >> 2) + i * 64;
            int kc = (tid & 3) * 4;
            int gn = bn + n;
            float4 bv = make_float4(0.f,0.f,0.f,0.f);
            if (gn < N) bv = *reinterpret_cast<const float4*>(Bm + (long)gn * K + k0 + kc);
            Bs[kc+0][n] = bv.x; Bs[kc+1][n] = bv.y; Bs[kc+2][n] = bv.z; Bs[kc+3][n] = bv.w;
        }
        __syncthreads();
        #pragma unroll
        for (int kk = 0; kk < BK; ++kk) {
            float a_s[4], b_s[8];
            {
                float4 t = *reinterpret_cast<const float4*>(&As[kk][ty*4]);
                a_s[0]=t.x; a_s[1]=t.y; a_s[2]=t.z; a_s[3]=t.w;
            }
            #pragma unroll
            for (int ni = 0; ni < 2; ++ni) {
                float4 t = *reinterpret_cast<const float4*>(&Bs[kk][tx*4 + ni*64]);
                b_s[ni*4+0]=t.x; b_s[ni*4+1]=t.y; b_s[ni*4+2]=t.z; b_s[ni*4+3]=t.w;
            }
            #pragma unroll
            for (int r = 0; r < 4; ++r)
                #pragma unroll
                for (int cc = 0; cc < 8; ++cc)
                    acc[r][cc] += a_s[r] * b_s[cc];
        }
        __syncthreads();
    }

    #pragma unroll
    for (int i = 0; i < 4; ++i) {
        int gm = bm + ty*4 + i;
        if (gm >= M) continue;
        float* crow = C + (long)gm * N;
        #pragma unroll
        for (int ni = 0; ni < 2; ++ni)
            #pragma unroll
            for (int j = 0; j < 4; ++j) {
                int gn = bn + ni*64 + tx*4 + j;
                if (gn >= N) continue;
                float v = acc[i][ni*4+j];
                crow[gn] = CLIP_ * tanhf(v * RSQ_E_) + auxz[(long)gm * N + gn];
            }
    }
}

// ---------------------------------------------------------------------------
// BatchNorm: stats (atomics) + apply (float4) with bf16 copy
// ---------------------------------------------------------------------------
__global__ __launch_bounds__(256) void bn_stats_kernel(
    const float* __restrict__ x, const float* __restrict__ y, float* __restrict__ sums)
{
    const int e  = threadIdx.x & 127;
    const int rh = threadIdx.x >> 7;
    const int base = blockIdx.x * 64;
    float s = 0.f, s2 = 0.f;
    for (int r = base + rh; r < base + 64; r += 2) {
        float v = x[(long)r * E_ + e] + y[(long)r * E_ + e];
        s += v; s2 += v * v;
    }
    atomicAdd(&sums[e], s);
    atomicAdd(&sums[E_ + e], s2);
}

__global__ void bn_apply_kernel(
    const float* __restrict__ x, const float* __restrict__ y,
    const float* __restrict__ sums, const float* __restrict__ g,
    const float* __restrict__ bb, float* __restrict__ o, ushort* __restrict__ obf)
{
    const float invR = 1.f / (float)ROWS_;
    const float4* x4 = (const float4*)x;
    const float4* y4 = (const float4*)y;
    const float4* s4 = (const float4*)sums;
    const float4* g4 = (const float4*)g;
    const float4* b4 = (const float4*)bb;
    float4* o4 = (float4*)o;
    int idx = blockIdx.x * blockDim.x + threadIdx.x;
    const int tot = ROWS_ * (E_/4);
    for (; idx < tot; idx += gridDim.x * blockDim.x) {
        int e4 = idx & 31;
        float4 sm = s4[e4], sq = s4[32 + e4], gg = g4[e4], bi = b4[e4];
        float4 xv = x4[idx], yv = y4[idx], ov;
        float m, var;
        m = sm.x*invR; var = sq.x*invR - m*m; ov.x = (xv.x+yv.x - m)*rsqrtf(var+EPS_)*gg.x + bi.x;
        m = sm.y*invR; var = sq.y*invR - m*m; ov.y = (xv.y+yv.y - m)*rsqrtf(var+EPS_)*gg.y + bi.y;
        m = sm.z*invR; var = sq.z*invR - m*m; ov.z = (xv.z+yv.z - m)*rsqrtf(var+EPS_)*gg.z + bi.z;
        m = sm.w*invR; var = sq.w*invR - m*m; ov.w = (xv.w+yv.w - m)*rsqrtf(var+EPS_)*gg.w + bi.w;
        o4[idx] = ov;
        ushort4 ub;
        ub.x = f2bf(ov.x); ub.y = f2bf(ov.y); ub.z = f2bf(ov.z); ub.w = f2bf(ov.w);
        *reinterpret_cast<ushort4*>(&obf[(size_t)idx * 4]) = ub;
    }
}

// ---------------------------------------------------------------------------
// Decoder: graph mean + q projection + capacity, fused; bf16 out.
// ---------------------------------------------------------------------------
__global__ __launch_bounds__(128) void qdec_kernel(
    const float* __restrict__ enc, const float* __restrict__ cap,
    const float* __restrict__ dWq, ushort* __restrict__ q)
{
    const int b = blockIdx.x, e = threadIdx.x;
    __shared__ float gr[E_];
    float s = 0.f;
    const float* p = enc + (long)b * P_ * E_ + e;
    for (int i = 0; i < P_; ++i) s += p[i * E_];
    gr[e] = s * (1.f / (float)P_);
    __syncthreads();
    float qg = 0.f;
    #pragma unroll 8
    for (int kk = 0; kk < E_; ++kk) qg += gr[kk] * dWq[kk * E_ + e];
    const float wc = dWq[E_ * E_ + e];
    for (int g = 0; g < G_; ++g)
        q[((long)b * G_ + g) * E_ + e] = f2bf(qg + cap[b * G_ + g] * wc);
}

// ---------------------------------------------------------------------------
// Row softmax over n
// ---------------------------------------------------------------------------
__global__ __launch_bounds__(256) void softmax_rows_kernel(
    const float* __restrict__ sc, float* __restrict__ outp)
{
    const int row  = blockIdx.x * 4 + (threadIdx.x >> 6);
    const int lane = threadIdx.x & 63;
    const float* sr = sc + (long)row * N_;
    float v[4];
    #pragma unroll
    for (int j = 0; j < 4; ++j) {
        int n = lane + j * 64;
        v[j] = (n < N_) ? sr[n] : -INFINITY;
    }
    float m = fmaxf(fmaxf(v[0], v[1]), fmaxf(v[2], v[3]));
    #pragma unroll
    for (int o = 1; o < 64; o <<= 1) m = fmaxf(m, __shfl_xor(m, o));
    float e[4], ss = 0.f;
    #pragma unroll
    for (int j = 0; j < 4; ++j) {
        int n = lane + j * 64;
        e[j] = (n < N_) ? __expf(v[j] - m) : 0.f;
        ss += e[j];
    }
    #pragma unroll
    for (int o = 1; o < 64; o <<= 1) ss += __shfl_xor(ss, o);
    float inv = 1.f / ss;
    #pragma unroll
    for (int j = 0; j < 4; ++j) {
        int n = lane + j * 64;
        if (n < N_) outp[(long)row * N_ + n] = e[j] * inv;
    }
}

// ---------------------------------------------------------------------------
// Host launcher
// ---------------------------------------------------------------------------
extern "C" void kernel_launch(void* const* d_in, const int* in_sizes, int n_in,
                              void* d_out, int out_size, void* d_ws, size_t ws_size,
                              hipStream_t stream)
{
    const float* item           = (const float*)d_in[0];
    const float* sols           = (const float*)d_in[1];
    const float* sols_mask      = (const float*)d_in[2];
    const float* capacity       = (const float*)d_in[3];
    const float* sols_mask_pomo = (const float*)d_in[4];
    const float* ninf_mask      = (const float*)d_in[5];
    const float* emb_W          = (const float*)d_in[6];
    const float* emb_b          = (const float*)d_in[7];
    const float* semb_W         = (const float*)d_in[8];
    const float* semb_b         = (const float*)d_in[9];
    const float* LWq            = (const float*)d_in[10];
    const float* LWk            = (const float*)d_in[11];
    const float* LWv            = (const float*)d_in[12];
    const float* Lcomb_W        = (const float*)d_in[13];
    const float* Lcomb_b        = (const float*)d_in[14];
    const float* Lcombs_W       = (const float*)d_in[15];
    const float* Lcombs_b       = (const float*)d_in[16];
    const float* Lbn1_g         = (const float*)d_in[17];
    const float* Lbn1_b         = (const float*)d_in[18];
    const float* Lff_W1         = (const float*)d_in[19];
    const float* Lff_b1         = (const float*)d_in[20];
    const float* Lff_W2         = (const float*)d_in[21];
    const float* Lff_b2         = (const float*)d_in[22];
    const float* Lbn2_g         = (const float*)d_in[23];
    const float* Lbn2_b         = (const float*)d_in[24];
    const float* dWq            = (const float*)d_in[25];
    const float* dWk            = (const float*)d_in[26];
    const float* dWv            = (const float*)d_in[27];
    const float* dcomb_W        = (const float*)d_in[28];
    const float* dcomb_b        = (const float*)d_in[29];
    const float* dWk_logit      = (const float*)d_in[30];

    float* w = (float*)d_ws;
    float*  buf_out = w;                                 // (B,P,E) f32        [0, 4.096M)
    ushort* x_bf    = (ushort*)(w + 4096000);            // (B,P,E) bf16       [4.096M, 6.144M)
    ushort* qkv_bf  = (ushort*)(w + 6144000);            // (B,P,384) bf16     [6.144M, 12.288M)
    float*  o1      = w + 12288000;                      // (B,P,E) f32        [12.288M, 16.384M)
    ushort* o1_bf   = (ushort*)(w + 16384000);           //                    [16.384M, 18.432M)
    float*  o2      = w + 18432000;                      //                    [18.432M, 22.528M)
    ushort* oc_bf   = (ushort*)(w + 22528000);           // (B,P,E) bf16       [22.528M, 24.576M)
    float*  mh      = w + 24576000;                      // (B,P,E) f32        [24.576M, 28.672M)
    ushort* ff1_bf  = (ushort*)(w + 28672000);           // (B,P,FF) bf16      [28.672M, 36.864M)
    // decoder aliases (encoder temporaries dead by then)
    ushort* dkv_bf  = (ushort*)(w + 12288000);           // (B,P,256) bf16  (o1 dead)
    float*  shk     = w + 18432000;                      // (B,N,E) f32     (o2 dead)
    ushort* qdec_bf = (ushort*)(w + 24576000);           // (B,G,E) bf16    (mh dead)
    ushort* ocd_bf  = (ushort*)(w + 25500000);           // (B,G,E) bf16
    float*  mhd     = w + 26400000;                      // (B,G,E) f32
    float*  scoreb  = w + 28672000;                      // (B,G,N) f32     (ff1_bf dead)
    // weights
    ushort* wts     = (ushort*)(w + 36864000);
    ushort* WqkvT  = wts;                // (L,384,128)   294,912
    ushort* WcombT = wts + 294912;       // (L,128,128)    98,304
    ushort* WcombsT= wts + 393216;
    ushort* Wff1T  = wts + 491520;       // (L,512,128)   393,216
    ushort* Wff2T  = wts + 884736;       // (L,128,512)   393,216
    ushort* WdkvT  = wts + 1277952;      // (256,128)      32,768
    ushort* WshkT  = wts + 1310720;      // (128,128)
    ushort* WmhdT  = wts + 1327104;      // (128,128)
    float*  sums   = w + 37600000;

    const long SPE  = (long)P_ * E_;     // 32000
    const long SPQ  = (long)P_ * 384;

    // ---- weight prep (bf16 transpose) ----
    wtrans<<<dim3(4,4,L_), 256, 0, stream>>>(LWq, WqkvT,             128, 128, 16384, 49152);
    wtrans<<<dim3(4,4,L_), 256, 0, stream>>>(LWk, WqkvT + 128*128,   128, 128, 16384, 49152);
    wtrans<<<dim3(4,4,L_), 256, 0, stream>>>(LWv, WqkvT + 256*128,   128, 128, 16384, 49152);
    wtrans<<<dim3(4,4,L_), 256, 0, stream>>>(Lcomb_W,  WcombT,       128, 128, 16384, 16384);
    wtrans<<<dim3(4,4,L_), 256, 0, stream>>>(Lcombs_W, WcombsT,      128, 128, 16384, 16384);
    wtrans<<<dim3(16,4,L_),256, 0, stream>>>(Lff_W1, Wff1T,          128, 512, 65536, 65536);
    wtrans<<<dim3(4,16,L_),256, 0, stream>>>(Lff_W2, Wff2T,          512, 128, 65536, 65536);
    wtrans<<<dim3(4,4,1),  256, 0, stream>>>(dWk, WdkvT,             128, 128, 0, 0);
    wtrans<<<dim3(4,4,1),  256, 0, stream>>>(dWv, WdkvT + 16384,     128, 128, 0, 0);
    wtrans<<<dim3(4,4,1),  256, 0, stream>>>(dWk_logit, WshkT,       128, 128, 0, 0);
    wtrans<<<dim3(4,4,1),  256, 0, stream>>>(dcomb_W, WmhdT,         128, 128, 0, 0);

    embed_kernel<<<2048, 256, 0, stream>>>(item, sols, emb_W, emb_b, semb_W, semb_b, buf_out, x_bf);

    dim3 ag(B_, H_, 4);
    for (int i = 0; i < L_; ++i) {
        // fused QKV (MFMA, bf16 out): (32000,128) @ (384,128)^T
        launch_mfma<1,0>(stream, x_bf, WqkvT + (long)i*384*128, nullptr,
                         qkv_bf, ROWS_, 384, 128, 0, 0, 0, 1);

        attn_mfma<0><<<ag, 256, 0, stream>>>(
            qkv_bf, 384, SPQ, P_,
            qkv_bf, 384, SPQ, 128,
            nullptr, sols_mask, oc_bf, SPE);

        launch_mfma<0,0>(stream, oc_bf, WcombT + (long)i*128*128, Lcomb_b + i*E_,
                         mh, N_, 128, 128, SPE, 0, SPE, B_);
        launch_mfma<0,0>(stream, oc_bf + N_*E_, WcombsT + (long)i*128*128, Lcombs_b + i*E_,
                         mh + N_*E_, S_, 128, 128, SPE, 0, SPE, B_);

        hipMemsetAsync(sums, 0, 2 * E_ * sizeof(float), stream);
        bn_stats_kernel<<<500, 256, 0, stream>>>(buf_out, mh, sums);
        bn_apply_kernel<<<1024, 256, 0, stream>>>(buf_out, mh, sums,
                                                  Lbn1_g + i*E_, Lbn1_b + i*E_, o1, o1_bf);

        launch_mfma<1,1>(stream, o1_bf, Wff1T + (long)i*512*128, Lff_b1 + (long)i*FF_,
                         ff1_bf, ROWS_, 512, 128, 0, 0, 0, 1);
        launch_mfma<0,0>(stream, ff1_bf, Wff2T + (long)i*128*512, Lff_b2 + i*E_,
                         o2, ROWS_, 128, 512, 0, 0, 0, 1);

        hipMemsetAsync(sums, 0, 2 * E_ * sizeof(float), stream);
        bn_stats_kernel<<<500, 256, 0, stream>>>(o1, o2, sums);
        bn_apply_kernel<<<1024, 256, 0, stream>>>(o1, o2, sums,
                                                  Lbn2_g + i*E_, Lbn2_b + i*E_, buf_out, x_bf);
    }

    // ---------------- decoder ----------------
    launch_mfma<1,0>(stream, x_bf, WdkvT, nullptr, dkv_bf, ROWS_, 256, 128, 0, 0, 0, 1);
    launch_mfma<0,0>(stream, x_bf, WshkT, nullptr, shk, N_, 128, 128, SPE, 0, (long)N_*E_, B_);
    qdec_kernel<<<B_, 128, 0, stream>>>(buf_out, capacity, dWq, qdec_bf);

    attn_mfma<1><<<dim3(B_, H_, 2), 256, 0, stream>>>(
        qdec_bf, 128, (long)G_*E_, G_,
        dkv_bf, 256, (long)P_*256, 0,
        ninf_mask, sols_mask_pomo, ocd_bf, (long)G_*E_);

    launch_mfma<0,0>(stream, ocd_bf, WmhdT, dcomb_b, mhd, B_*G_, 128, 128, 0, 0, 0, 1);

    // score: CLIP*tanh((mhd @ shk^T)*RSQ_E) + ninf, then row softmax
    dim3 sg(2, 2, B_);
    gemm_score<<<sg, 256, 0, stream>>>(mhd, shk, ninf_mask, scoreb,
                                       G_, N_, E_, (long)G_*E_, (long)N_*E_, (long)G_*N_);
    softmax_rows_kernel<<<(B_*G_)/4, 256, 0, stream>>>(scoreb, (float*)d_out);
}

// Round 10
// 1108.417 us; speedup vs baseline: 3.3293x; 1.3490x over previous
//
#include <hip/hip_runtime.h>
#include <math.h>

#define E_   128
#define H_   8
#define KD_  16
#define FF_  512
#define L_   6
#define N_   200
#define S_   50
#define G_   100
#define B_   128
#define P_   250          // N_ + S_
#define ROWS_ (B_*P_)     // 32000
#define CLIP_ 10.0f
#define EPS_  1e-5f
#define RSQ_KD_ 0.25f
#define RSQ_E_  0.08838834764831845f

typedef __attribute__((ext_vector_type(8))) short short8;
typedef __attribute__((ext_vector_type(4))) float f32x4;

__device__ __forceinline__ ushort f2bf(float f) {
    union { float f; unsigned u; } v; v.f = f;
    unsigned u = v.u;
    return (ushort)((u + 0x7FFFu + ((u >> 16) & 1u)) >> 16);
}
__device__ __forceinline__ float bf2f(ushort u) {
    union { unsigned u; float f; } v; v.u = ((unsigned)u) << 16; return v.f;
}

// ---------------------------------------------------------------------------
// Embedding: f32 + bf16 out
// ---------------------------------------------------------------------------
__global__ void embed_kernel(const float* __restrict__ item, const float* __restrict__ sols,
                             const float* __restrict__ embW, const float* __restrict__ embB,
                             const float* __restrict__ sembW, const float* __restrict__ sembB,
                             float* __restrict__ out, ushort* __restrict__ obf)
{
    int idx = blockIdx.x * blockDim.x + threadIdx.x;
    const int total = ROWS_ * E_;
    for (; idx < total; idx += gridDim.x * blockDim.x) {
        int e = idx & (E_ - 1);
        int r = idx >> 7;
        int b = r / P_, p = r % P_;
        float val;
        if (p < N_) {
            const float* it = item + ((long)b * N_ + p) * 3;
            val = it[0]*embW[e] + it[1]*embW[E_+e] + it[2]*embW[2*E_+e] + embB[e];
        } else {
            int s = p - N_;
            const float* sl = sols + ((long)b * S_ + s) * 2;
            val = sl[0]*sembW[e] + sl[1]*sembW[E_+e] + sembB[e];
        }
        out[idx] = val;
        obf[idx] = f2bf(val);
    }
}

// ---------------------------------------------------------------------------
// Weight transpose+convert: src (Z,K,N) f32 -> dst (Z,N,K) bf16
// ---------------------------------------------------------------------------
__global__ __launch_bounds__(256) void wtrans(const float* __restrict__ src, ushort* __restrict__ dst,
                                              int K, int N, long srcZ, long dstZ)
{
    __shared__ float t[32][33];
    src += (size_t)blockIdx.z * srcZ;
    dst += (size_t)blockIdx.z * dstZ;
    const int k0 = blockIdx.y * 32, n0 = blockIdx.x * 32;
    const int tr = threadIdx.x >> 3, tc4 = (threadIdx.x & 7) * 4;
    float4 v = *reinterpret_cast<const float4*>(&src[(size_t)(k0 + tr) * N + n0 + tc4]);
    t[tr][tc4+0] = v.x; t[tr][tc4+1] = v.y; t[tr][tc4+2] = v.z; t[tr][tc4+3] = v.w;
    __syncthreads();
    ushort4 o;
    o.x = f2bf(t[tc4+0][tr]); o.y = f2bf(t[tc4+1][tr]);
    o.z = f2bf(t[tc4+2][tr]); o.w = f2bf(t[tc4+3][tr]);
    *reinterpret_cast<ushort4*>(&dst[(size_t)(n0 + tr) * K + k0 + tc4]) = o;
}

// ---------------------------------------------------------------------------
// MFMA bf16 GEMM: C[z] = act(A[z] @ Bt[z]^T + bias)
// STATS=1: s = v + residF (f32); C := s (f32); atomicAdd col sum/sumsq (f32).
// ---------------------------------------------------------------------------
template<int OUTBF, int RELU, int STATS>
__global__ __launch_bounds__(256) void gemm_mfma(
    const ushort* __restrict__ A, const ushort* __restrict__ Bt,
    const float* __restrict__ bias, void* __restrict__ Cv,
    const float* __restrict__ residF, float* __restrict__ sums,
    int M, int N, int K, long sA, long sBt, long sC)
{
    __shared__ ushort As[128*32];
    __shared__ ushort Bs[128*32];
    A  += (size_t)blockIdx.z * sA;
    Bt += (size_t)blockIdx.z * sBt;
    const int m0 = blockIdx.y * 128, n0 = blockIdx.x * 128;
    const int tid = threadIdx.x, w = tid >> 6, l = tid & 63;
    const int wr = w >> 1, wc = w & 1;

    f32x4 acc[4][4];
    #pragma unroll
    for (int i = 0; i < 4; ++i)
        #pragma unroll
        for (int j = 0; j < 4; ++j)
            acc[i][j] = (f32x4){0.f, 0.f, 0.f, 0.f};

    int srow[2], scg[2];
    #pragma unroll
    for (int i = 0; i < 2; ++i) {
        int flat = i*4096 + w*1024 + l*16;
        int row = flat >> 6, cl = (flat >> 4) & 3;
        srow[i] = row;
        scg[i]  = cl ^ ((row >> 1) & 3);
    }

    for (int k0 = 0; k0 < K; k0 += 32) {
        #pragma unroll
        for (int i = 0; i < 2; ++i) {
            int ga = m0 + srow[i]; if (ga >= M) ga = M - 1;
            const ushort* gpa = A + (size_t)ga * K + k0 + scg[i]*8;
            __builtin_amdgcn_global_load_lds((const __attribute__((address_space(1))) void*)gpa,
                (__attribute__((address_space(3))) void*)(As + i*2048 + w*512), 16, 0, 0);
            const ushort* gpb = Bt + (size_t)(n0 + srow[i]) * K + k0 + scg[i]*8;
            __builtin_amdgcn_global_load_lds((const __attribute__((address_space(1))) void*)gpb,
                (__attribute__((address_space(3))) void*)(Bs + i*2048 + w*512), 16, 0, 0);
        }
        __syncthreads();

        short8 a[4], b[4];
        #pragma unroll
        for (int mi = 0; mi < 4; ++mi) {
            int row = wr*64 + mi*16 + (l & 15);
            int ch = (l >> 4) ^ ((row >> 1) & 3);
            a[mi] = *reinterpret_cast<const short8*>(&As[row*32 + ch*8]);
        }
        #pragma unroll
        for (int ni = 0; ni < 4; ++ni) {
            int row = wc*64 + ni*16 + (l & 15);
            int ch = (l >> 4) ^ ((row >> 1) & 3);
            b[ni] = *reinterpret_cast<const short8*>(&Bs[row*32 + ch*8]);
        }
        #pragma unroll
        for (int mi = 0; mi < 4; ++mi)
            #pragma unroll
            for (int ni = 0; ni < 4; ++ni)
                acc[mi][ni] = __builtin_amdgcn_mfma_f32_16x16x32_bf16(a[mi], b[ni], acc[mi][ni], 0, 0, 0);
        __syncthreads();
    }

    float bv[4];
    #pragma unroll
    for (int ni = 0; ni < 4; ++ni)
        bv[ni] = bias ? bias[n0 + wc*64 + ni*16 + (l & 15)] : 0.f;

    float*  Cf = (float*)Cv  + (size_t)blockIdx.z * sC;
    ushort* Cb = (ushort*)Cv + (size_t)blockIdx.z * sC;
    const float* Rf = STATS ? (residF + (size_t)blockIdx.z * sC) : nullptr;

    float csum[4] = {0.f,0.f,0.f,0.f}, csq[4] = {0.f,0.f,0.f,0.f};

    #pragma unroll
    for (int mi = 0; mi < 4; ++mi)
        #pragma unroll
        for (int j = 0; j < 4; ++j) {
            int row = m0 + wr*64 + mi*16 + (l >> 4)*4 + j;
            if (row >= M) continue;
            #pragma unroll
            for (int ni = 0; ni < 4; ++ni) {
                int col = n0 + wc*64 + ni*16 + (l & 15);
                float v = acc[mi][ni][j] + bv[ni];
                if (RELU) v = fmaxf(v, 0.f);
                if (STATS) {
                    float s = v + Rf[(size_t)row * N + col];
                    csum[ni] += s; csq[ni] += s * s;
                    Cf[(size_t)row * N + col] = s;
                } else if (OUTBF) {
                    Cb[(size_t)row * N + col] = f2bf(v);
                } else {
                    Cf[(size_t)row * N + col] = v;
                }
            }
        }

    if (STATS) {
        #pragma unroll
        for (int ni = 0; ni < 4; ++ni) {
            csum[ni] += __shfl_xor(csum[ni], 16); csum[ni] += __shfl_xor(csum[ni], 32);
            csq[ni]  += __shfl_xor(csq[ni], 16);  csq[ni]  += __shfl_xor(csq[ni], 32);
        }
        if ((l >> 4) == 0) {
            #pragma unroll
            for (int ni = 0; ni < 4; ++ni) {
                int col = n0 + wc*64 + ni*16 + (l & 15);
                atomicAdd(&sums[col], csum[ni]);
                atomicAdd(&sums[128 + col], csq[ni]);
            }
        }
    }
}

template<int OUTBF, int RELU>
static inline void launch_mfma(hipStream_t st, const ushort* A, const ushort* Bt, const float* bias,
                               void* C, int M, int N, int K, long sA, long sBt, long sC, int Z)
{
    dim3 g(N / 128, (M + 127) / 128, Z);
    gemm_mfma<OUTBF, RELU, 0><<<g, 256, 0, st>>>(A, Bt, bias, C, nullptr, nullptr, M, N, K, sA, sBt, sC);
}
static inline void launch_mfma_stats(hipStream_t st, const ushort* A, const ushort* Bt, const float* bias,
                                     float* C, const float* resid, float* sums,
                                     int M, int N, int K, long sA, long sBt, long sC, int Z)
{
    dim3 g(N / 128, (M + 127) / 128, Z);
    gemm_mfma<0, 0, 1><<<g, 256, 0, st>>>(A, Bt, bias, C, resid, sums, M, N, K, sA, sBt, sC);
}

// ---------------------------------------------------------------------------
// MFMA fused attention v2 (all-bf16 MFMA, R4-proven numerics):
// one block per (b,h); 4 waves; wave handles 16-query sub-tiles qt=wv,wv+4,...
// K+V staged in LDS once; K-frags cached in regs; masks pre-staged (MODE 0).
// Segments: keys 0..199 (seg1), 200..249 (seg2), 250..255 pad (-1e30).
// MODE 0 (encoder): seg2 mask m2p[b*50+k-200]; queries>=200 use seg1 only.
// MODE 1 (decoder): seg1 m1p[(b*G+q)*200+k]; seg2 m2p[(b*G+q)*50+k-200].
// ---------------------------------------------------------------------------
#define VT_OFF   8192
#define P_OFF    16640
#define MSK_OFF  50432
template<int MODE>
__global__ __launch_bounds__(256) void attn_mfma2(
    const ushort* __restrict__ qb, int qrs, long qbs, int Pq,
    const ushort* __restrict__ kvb, int krs, long kbs, int kcol0,
    const float* __restrict__ m1p, const float* __restrict__ m2p,
    ushort* __restrict__ out, long so)
{
    __shared__ __align__(16) char smem[51456];
    const int b = blockIdx.x, h = blockIdx.y;
    const int tid = threadIdx.x;
    const int l = tid & 63, wv = tid >> 6;
    const int c = l >> 4, lq = l & 15;
    const short8 zv = {0,0,0,0,0,0,0,0};

    // ---- stage K (bf16): chunk-major Kc[ch][key], keys>=P_ zero ----
    {
        short8 k0v = zv, k1v = zv;
        if (tid < P_) {
            const ushort* kr = kvb + (size_t)b * kbs + (size_t)tid * krs + kcol0 + h * 16;
            k0v = *reinterpret_cast<const short8*>(kr);
            k1v = *reinterpret_cast<const short8*>(kr + 8);
        }
        *reinterpret_cast<short8*>(smem + tid * 16)        = k0v;
        *reinterpret_cast<short8*>(smem + 4096 + tid * 16) = k1v;
    }
    // ---- stage V transposed (bf16 bit-copy): Vt[d][key], row stride 528 B ----
    if (tid < 128) {
        const int k0 = tid * 2;
        const int vcol = kcol0 + 128 + h * 16;
        short8 va0 = zv, va1 = zv, vb0 = zv, vb1 = zv;
        if (k0 < P_) {
            const ushort* vr = kvb + (size_t)b * kbs + (size_t)k0 * krs + vcol;
            va0 = *reinterpret_cast<const short8*>(vr);
            va1 = *reinterpret_cast<const short8*>(vr + 8);
        }
        if (k0 + 1 < P_) {
            const ushort* vr = kvb + (size_t)b * kbs + (size_t)(k0 + 1) * krs + vcol;
            vb0 = *reinterpret_cast<const short8*>(vr);
            vb1 = *reinterpret_cast<const short8*>(vr + 8);
        }
        #pragma unroll
        for (int d = 0; d < 16; ++d) {
            ushort e0 = (ushort)(d < 8 ? va0[d] : va1[d - 8]);
            ushort e1 = (ushort)(d < 8 ? vb0[d] : vb1[d - 8]);
            *reinterpret_cast<uint*>(smem + VT_OFF + d * 528 + tid * 4) = (uint)e0 | ((uint)e1 << 16);
        }
    }
    // ---- stage mask (MODE 0) ----
    if constexpr (MODE == 0) {
        float mv = 0.f;
        if (tid >= N_ && tid < P_) mv = m2p[b * S_ + tid - N_];
        else if (tid >= P_)        mv = -1e30f;
        reinterpret_cast<float*>(smem + MSK_OFF)[tid] = mv;
    }
    __syncthreads();

    // ---- K-fragments cached in registers ----
    short8 kf[16];
    #pragma unroll
    for (int kt = 0; kt < 16; ++kt)
        kf[kt] = (c < 2) ? *reinterpret_cast<const short8*>(smem + c*4096 + (kt*16 + lq)*16) : zv;

    f32x4 mreg[4];
    if constexpr (MODE == 0) {
        #pragma unroll
        for (int i = 0; i < 4; ++i)
            mreg[i] = *reinterpret_cast<const f32x4*>(smem + MSK_OFF + ((12 + i)*16 + c*4) * 4);
    }

    char* Pw = smem + P_OFF + wv * 8448;
    const int gl = c * 4;

    for (int qt = wv; qt * 16 < Pq; qt += 4) {
        const int qg = qt * 16 + lq;
        const int qc = (qg < Pq) ? qg : (Pq - 1);
        short8 qf = zv;
        if (c < 2) qf = *reinterpret_cast<const short8*>(
            qb + (size_t)b * qbs + (size_t)qc * qrs + h * 16 + c * 8);

        f32x4 sacc[16];
        #pragma unroll
        for (int kt = 0; kt < 16; ++kt) sacc[kt] = (f32x4){0.f,0.f,0.f,0.f};
        #pragma unroll
        for (int kt = 0; kt < 16; ++kt)
            sacc[kt] = __builtin_amdgcn_mfma_f32_16x16x32_bf16(kf[kt], qf, sacc[kt], 0, 0, 0);

        // ---- segmented softmax ----
        float m1 = -3e38f, m2 = -3e38f;
        const float* m1row = nullptr; const float* m2row = nullptr;
        if constexpr (MODE == 1) {
            m1row = m1p + ((size_t)b * G_ + qc) * N_;
            m2row = m2p + ((size_t)b * G_ + qc) * S_;
        }
        #pragma unroll
        for (int kt = 0; kt < 16; ++kt) {
            #pragma unroll
            for (int j = 0; j < 4; ++j) {
                int key = kt * 16 + gl + j;
                float s;
                if constexpr (MODE == 0) {
                    if (kt < 12) s = sacc[kt][j] * RSQ_KD_;
                    else         s = fmaf(sacc[kt][j], RSQ_KD_, mreg[kt-12][j]);
                } else {
                    float mv = (key < N_) ? m1row[key] : (key < P_ ? m2row[key - N_] : -1e30f);
                    s = fmaf(sacc[kt][j], RSQ_KD_, mv);
                }
                sacc[kt][j] = s;
                if (key < N_) m1 = fmaxf(m1, s);
                else          m2 = fmaxf(m2, s);
            }
        }
        m1 = fmaxf(m1, __shfl_xor(m1, 16)); m1 = fmaxf(m1, __shfl_xor(m1, 32));
        m2 = fmaxf(m2, __shfl_xor(m2, 16)); m2 = fmaxf(m2, __shfl_xor(m2, 32));

        float s1 = 0.f, s2 = 0.f;
        #pragma unroll
        for (int kt = 0; kt < 16; ++kt) {
            #pragma unroll
            for (int j = 0; j < 4; ++j) {
                int key = kt * 16 + gl + j;
                float p = __expf(sacc[kt][j] - (key < N_ ? m1 : m2));
                if (key < N_) s1 += p; else s2 += p;
                sacc[kt][j] = p;
            }
        }
        s1 += __shfl_xor(s1, 16); s1 += __shfl_xor(s1, 32);
        s2 += __shfl_xor(s2, 16); s2 += __shfl_xor(s2, 32);
        const float sc1 = 1.f / s1;
        float sc2 = 1.f / s2;
        if constexpr (MODE == 0) { if (qg >= N_) sc2 = 0.f; }

        // ---- P -> bf16 -> per-wave LDS ----
        #pragma unroll
        for (int kt = 0; kt < 16; ++kt) {
            float p0 = sacc[kt][0] * ((kt*16+gl+0) < N_ ? sc1 : sc2);
            float p1 = sacc[kt][1] * ((kt*16+gl+1) < N_ ? sc1 : sc2);
            float p2 = sacc[kt][2] * ((kt*16+gl+2) < N_ ? sc1 : sc2);
            float p3 = sacc[kt][3] * ((kt*16+gl+3) < N_ ? sc1 : sc2);
            uint u01, u23;
            asm("v_cvt_pk_bf16_f32 %0, %1, %2" : "=v"(u01) : "v"(p0), "v"(p1));
            asm("v_cvt_pk_bf16_f32 %0, %1, %2" : "=v"(u23) : "v"(p2), "v"(p3));
            uint2 uu; uu.x = u01; uu.y = u23;
            *reinterpret_cast<uint2*>(Pw + lq * 528 + kt * 32 + gl * 2) = uu;
        }

        // ---- O^T = V^T . P^T (bf16 MFMA) ----
        f32x4 oa = (f32x4){0.f,0.f,0.f,0.f};
        #pragma unroll
        for (int ks = 0; ks < 8; ++ks) {
            short8 af = *reinterpret_cast<const short8*>(smem + VT_OFF + lq * 528 + ks * 64 + c * 16);
            short8 pf = *reinterpret_cast<const short8*>(Pw + lq * 528 + ks * 64 + c * 16);
            oa = __builtin_amdgcn_mfma_f32_16x16x32_bf16(af, pf, oa, 0, 0, 0);
        }

        if (qg < Pq) {
            ushort4 u;
            u.x = f2bf(oa[0]); u.y = f2bf(oa[1]); u.z = f2bf(oa[2]); u.w = f2bf(oa[3]);
            *reinterpret_cast<ushort4*>(out + (size_t)b * so + (size_t)qg * E_ + h * 16 + gl) = u;
        }
    }
}

// ---------------------------------------------------------------------------
// BN apply: f32 in -> f32 + bf16 out, scale/shift precomputed in LDS
// ---------------------------------------------------------------------------
__global__ __launch_bounds__(256) void bn_apply(
    const float* __restrict__ s, const float* __restrict__ sums,
    const float* __restrict__ g, const float* __restrict__ bb,
    float* __restrict__ o, ushort* __restrict__ obf)
{
    __shared__ float sc[128], sh[128];
    const int t = threadIdx.x;
    if (t < 128) {
        const float invR = 1.f / (float)ROWS_;
        float m = sums[t] * invR;
        float var = sums[128 + t] * invR - m * m;
        float scale = g[t] * rsqrtf(var + EPS_);
        sc[t] = scale; sh[t] = bb[t] - m * scale;
    }
    __syncthreads();
    int idx = blockIdx.x * 256 + t;
    const int tot = ROWS_ * E_ / 4;
    for (; idx < tot; idx += gridDim.x * 256) {
        const int e0 = (idx & 31) * 4;
        float4 v = reinterpret_cast<const float4*>(s)[idx];
        float4 r;
        r.x = v.x * sc[e0+0] + sh[e0+0];
        r.y = v.y * sc[e0+1] + sh[e0+1];
        r.z = v.z * sc[e0+2] + sh[e0+2];
        r.w = v.w * sc[e0+3] + sh[e0+3];
        reinterpret_cast<float4*>(o)[idx] = r;
        ushort4 ub;
        ub.x = f2bf(r.x); ub.y = f2bf(r.y); ub.z = f2bf(r.z); ub.w = f2bf(r.w);
        reinterpret_cast<ushort4*>(obf)[idx] = ub;
    }
}

// ---------------------------------------------------------------------------
// fp32 GEMM for the score path: C = CLIP*tanh((A@B^T)*RSQ_E) + aux
// ---------------------------------------------------------------------------
__global__ __launch_bounds__(256) void gemm_score(
    const float* __restrict__ A, const float* __restrict__ Bm,
    const float* __restrict__ aux, float* __restrict__ C,
    int M, int N, int K, long sA, long sB, long sC)
{
    constexpr int BM = 64, BN = 128, BK = 16;
    A  += (long)blockIdx.z * sA;
    Bm += (long)blockIdx.z * sB;
    C  += (long)blockIdx.z * sC;
    const float* auxz = aux + (long)blockIdx.z * sC;
    const int bm = blockIdx.y * BM, bn = blockIdx.x * BN;

    __shared__ float As[BK][BM + 4];
    __shared__ float Bs[BK][BN + 4];
    const int tid = threadIdx.x;
    const int tx = tid & 15, ty = tid >> 4;
    float acc[4][8] = {};

    for (int k0 = 0; k0 < K; k0 += BK) {
        {
            int m  = tid >> 2;
            int kc = (tid & 3) * 4;
            int gm = bm + m;
            float4 av = make_float4(0.f,0.f,0.f,0.f);
            if (gm < M) av = *reinterpret_cast<const float4*>(A + (long)gm * K + k0 + kc);
            As[kc+0][m] = av.x; As[kc+1][m] = av.y; As[kc+2][m] = av.z; As[kc+3][m] = av.w;
        }
        #pragma unroll
        for (int i = 0; i < 2; ++i) {
            int n  = (tid >> 2) + i * 64;
            int kc = (tid & 3) * 4;
            int gn = bn + n;
            float4 bv = make_float4(0.f,0.f,0.f,0.f);
            if (gn < N) bv = *reinterpret_cast<const float4*>(Bm + (long)gn * K + k0 + kc);
            Bs[kc+0][n] = bv.x; Bs[kc+1][n] = bv.y; Bs[kc+2][n] = bv.z; Bs[kc+3][n] = bv.w;
        }
        __syncthreads();
        #pragma unroll
        for (int kk = 0; kk < BK; ++kk) {
            float a_s[4], b_s[8];
            {
                float4 t = *reinterpret_cast<const float4*>(&As[kk][ty*4]);
                a_s[0]=t.x; a_s[1]=t.y; a_s[2]=t.z; a_s[3]=t.w;
            }
            #pragma unroll
            for (int ni = 0; ni < 2; ++ni) {
                float4 t = *reinterpret_cast<const float4*>(&Bs[kk][tx*4 + ni*64]);
                b_s[ni*4+0]=t.x; b_s[ni*4+1]=t.y; b_s[ni*4+2]=t.z; b_s[ni*4+3]=t.w;
            }
            #pragma unroll
            for (int r = 0; r < 4; ++r)
                #pragma unroll
                for (int cc = 0; cc < 8; ++cc)
                    acc[r][cc] += a_s[r] * b_s[cc];
        }
        __syncthreads();
    }

    #pragma unroll
    for (int i = 0; i < 4; ++i) {
        int gm = bm + ty*4 + i;
        if (gm >= M) continue;
        float* crow = C + (long)gm * N;
        #pragma unroll
        for (int ni = 0; ni < 2; ++ni)
            #pragma unroll
            for (int j = 0; j < 4; ++j) {
                int gn = bn + ni*64 + tx*4 + j;
                if (gn >= N) continue;
                float v = acc[i][ni*4+j];
                crow[gn] = CLIP_ * tanhf(v * RSQ_E_) + auxz[(long)gm * N + gn];
            }
    }
}

// ---------------------------------------------------------------------------
// Decoder: graph mean (f32 in) + q projection + capacity -> bf16 q
// ---------------------------------------------------------------------------
__global__ __launch_bounds__(128) void qdec_kernel(
    const float* __restrict__ enc, const float* __restrict__ cap,
    const float* __restrict__ dWq, ushort* __restrict__ q)
{
    const int b = blockIdx.x, e = threadIdx.x;
    __shared__ float gr[E_];
    float s = 0.f;
    const float* p = enc + (size_t)b * P_ * E_ + e;
    for (int i = 0; i < P_; ++i) s += p[i * E_];
    gr[e] = s * (1.f / (float)P_);
    __syncthreads();
    float qg = 0.f;
    #pragma unroll 8
    for (int kk = 0; kk < E_; ++kk) qg += gr[kk] * dWq[kk * E_ + e];
    const float wc = dWq[E_ * E_ + e];
    for (int g = 0; g < G_; ++g)
        q[((size_t)b * G_ + g) * E_ + e] = f2bf(qg + cap[b * G_ + g] * wc);
}

// ---------------------------------------------------------------------------
// Row softmax over n
// ---------------------------------------------------------------------------
__global__ __launch_bounds__(256) void softmax_rows_kernel(
    const float* __restrict__ sc, float* __restrict__ outp)
{
    const int row  = blockIdx.x * 4 + (threadIdx.x >> 6);
    const int lane = threadIdx.x & 63;
    const float* sr = sc + (long)row * N_;
    float v[4];
    #pragma unroll
    for (int j = 0; j < 4; ++j) {
        int n = lane + j * 64;
        v[j] = (n < N_) ? sr[n] : -INFINITY;
    }
    float m = fmaxf(fmaxf(v[0], v[1]), fmaxf(v[2], v[3]));
    #pragma unroll
    for (int o = 1; o < 64; o <<= 1) m = fmaxf(m, __shfl_xor(m, o));
    float e[4], ss = 0.f;
    #pragma unroll
    for (int j = 0; j < 4; ++j) {
        int n = lane + j * 64;
        e[j] = (n < N_) ? __expf(v[j] - m) : 0.f;
        ss += e[j];
    }
    #pragma unroll
    for (int o = 1; o < 64; o <<= 1) ss += __shfl_xor(ss, o);
    float inv = 1.f / ss;
    #pragma unroll
    for (int j = 0; j < 4; ++j) {
        int n = lane + j * 64;
        if (n < N_) outp[(long)row * N_ + n] = e[j] * inv;
    }
}

// ---------------------------------------------------------------------------
// Host launcher
// ---------------------------------------------------------------------------
extern "C" void kernel_launch(void* const* d_in, const int* in_sizes, int n_in,
                              void* d_out, int out_size, void* d_ws, size_t ws_size,
                              hipStream_t stream)
{
    const float* item           = (const float*)d_in[0];
    const float* sols           = (const float*)d_in[1];
    const float* sols_mask      = (const float*)d_in[2];
    const float* capacity       = (const float*)d_in[3];
    const float* sols_mask_pomo = (const float*)d_in[4];
    const float* ninf_mask      = (const float*)d_in[5];
    const float* emb_W          = (const float*)d_in[6];
    const float* emb_b          = (const float*)d_in[7];
    const float* semb_W         = (const float*)d_in[8];
    const float* semb_b         = (const float*)d_in[9];
    const float* LWq            = (const float*)d_in[10];
    const float* LWk            = (const float*)d_in[11];
    const float* LWv            = (const float*)d_in[12];
    const float* Lcomb_W        = (const float*)d_in[13];
    const float* Lcomb_b        = (const float*)d_in[14];
    const float* Lcombs_W       = (const float*)d_in[15];
    const float* Lcombs_b       = (const float*)d_in[16];
    const float* Lbn1_g         = (const float*)d_in[17];
    const float* Lbn1_b         = (const float*)d_in[18];
    const float* Lff_W1         = (const float*)d_in[19];
    const float* Lff_b1         = (const float*)d_in[20];
    const float* Lff_W2         = (const float*)d_in[21];
    const float* Lff_b2         = (const float*)d_in[22];
    const float* Lbn2_g         = (const float*)d_in[23];
    const float* Lbn2_b         = (const float*)d_in[24];
    const float* dWq            = (const float*)d_in[25];
    const float* dWk            = (const float*)d_in[26];
    const float* dWv            = (const float*)d_in[27];
    const float* dcomb_W        = (const float*)d_in[28];
    const float* dcomb_b        = (const float*)d_in[29];
    const float* dWk_logit      = (const float*)d_in[30];

    // ---- workspace layout (float units). Audited:
    //   x      f32  (B,P,E)  = 4,096,000 f              [0,          4,096,000)
    //   x_bf   bf16 (B,P,E)  = 4,096,000 u = 2,048,000 f [4,096,000,  6,144,000)
    //   qkv_bf bf16 (B,P,384)= 12,288,000 u = 6,144,000 f [6,144,000, 12,288,000)
    //   oc_bf  bf16 (B,P,E)  = 2,048,000 f              [12,288,000, 14,336,000)
    //   sbuf   f32  (B,P,E)  = 4,096,000 f              [14,336,000, 18,432,000)
    //   o1     f32  (B,P,E)  = 4,096,000 f              [18,432,000, 22,528,000)
    //   o1_bf  bf16 (B,P,E)  = 2,048,000 f              [22,528,000, 24,576,000)
    //   ff1_bf bf16 (B,P,FF) = 8,192,000 f              [24,576,000, 32,768,000)
    float* w = (float*)d_ws;
    float*  x       = w;
    ushort* x_bf    = (ushort*)(w + 4096000);
    ushort* qkv_bf  = (ushort*)(w + 6144000);
    ushort* oc_bf   = (ushort*)(w + 12288000);
    float*  sbuf    = w + 14336000;
    float*  o1      = w + 18432000;
    ushort* o1_bf   = (ushort*)(w + 22528000);
    ushort* ff1_bf  = (ushort*)(w + 24576000);
    // decoder aliases (encoder temporaries dead at decoder time):
    ushort* dkv_bf  = (ushort*)(w + 6144000);   // (B,P,256) bf16 = 4,096,000 f (qkv dead)
    float*  shk     = w + 14336000;             // (B,N,E) f32 = 3,276,800 f (sbuf dead)
    ushort* qdec_bf = (ushort*)(w + 18432000);  // (B,G,E) bf16 = 819,200 f (o1 dead)
    ushort* ocd_bf  = (ushort*)(w + 19300000);  // (B,G,E) bf16 = 819,200 f
    float*  mhd     = w + 20200000;             // (B,G,E) f32 = 1,638,400 f (ends 21,838,400)
    float*  scoreb  = w + 24576000;             // (B,G,N) f32 = 2,560,000 f (ff1 dead)
    // weights (bf16) at [32,768,000, ~33,440,000)
    ushort* wts     = (ushort*)(w + 32768000);
    ushort* WqkvT  = wts;                // (L,384,128)
    ushort* WcombT = wts + 294912;       // (L,128,128)
    ushort* WcombsT= wts + 393216;
    ushort* Wff1T  = wts + 491520;       // (L,512,128)
    ushort* Wff2T  = wts + 884736;       // (L,128,512)
    ushort* WdkvT  = wts + 1277952;      // (256,128)
    ushort* WshkT  = wts + 1310720;
    ushort* WmhdT  = wts + 1327104;
    float*  sums_all = w + 33500000;     // (L,2,256) floats

    const long SPE  = (long)P_ * E_;     // 32000
    const long SPQ  = (long)P_ * 384;

    // ---- weight prep ----
    wtrans<<<dim3(4,4,L_), 256, 0, stream>>>(LWq, WqkvT,             128, 128, 16384, 49152);
    wtrans<<<dim3(4,4,L_), 256, 0, stream>>>(LWk, WqkvT + 128*128,   128, 128, 16384, 49152);
    wtrans<<<dim3(4,4,L_), 256, 0, stream>>>(LWv, WqkvT + 256*128,   128, 128, 16384, 49152);
    wtrans<<<dim3(4,4,L_), 256, 0, stream>>>(Lcomb_W,  WcombT,       128, 128, 16384, 16384);
    wtrans<<<dim3(4,4,L_), 256, 0, stream>>>(Lcombs_W, WcombsT,      128, 128, 16384, 16384);
    wtrans<<<dim3(16,4,L_),256, 0, stream>>>(Lff_W1, Wff1T,          128, 512, 65536, 65536);
    wtrans<<<dim3(4,16,L_),256, 0, stream>>>(Lff_W2, Wff2T,          512, 128, 65536, 65536);
    wtrans<<<dim3(4,4,1),  256, 0, stream>>>(dWk, WdkvT,             128, 128, 0, 0);
    wtrans<<<dim3(4,4,1),  256, 0, stream>>>(dWv, WdkvT + 16384,     128, 128, 0, 0);
    wtrans<<<dim3(4,4,1),  256, 0, stream>>>(dWk_logit, WshkT,       128, 128, 0, 0);
    wtrans<<<dim3(4,4,1),  256, 0, stream>>>(dcomb_W, WmhdT,         128, 128, 0, 0);

    (void)hipMemsetAsync(sums_all, 0, L_ * 2 * 256 * sizeof(float), stream);
    embed_kernel<<<2048, 256, 0, stream>>>(item, sols, emb_W, emb_b, semb_W, semb_b, x, x_bf);

    dim3 ag(B_, H_);
    for (int i = 0; i < L_; ++i) {
        float* sums1 = sums_all + i * 512;
        float* sums2 = sums1 + 256;

        launch_mfma<1,0>(stream, x_bf, WqkvT + (long)i*384*128, nullptr,
                         qkv_bf, ROWS_, 384, 128, 0, 0, 0, 1);

        attn_mfma2<0><<<ag, 256, 0, stream>>>(
            qkv_bf, 384, SPQ, P_,
            qkv_bf, 384, SPQ, 128,
            nullptr, sols_mask, oc_bf, SPE);

        // comb GEMMs: s = x + comb(oc) (f32) + stats
        launch_mfma_stats(stream, oc_bf, WcombT + (long)i*128*128, Lcomb_b + i*E_,
                          sbuf, x, sums1, N_, 128, 128, SPE, 0, SPE, B_);
        launch_mfma_stats(stream, oc_bf + N_*E_, WcombsT + (long)i*128*128, Lcombs_b + i*E_,
                          sbuf + N_*E_, x + N_*E_, sums1, S_, 128, 128, SPE, 0, SPE, B_);

        bn_apply<<<2048, 256, 0, stream>>>(sbuf, sums1, Lbn1_g + i*E_, Lbn1_b + i*E_, o1, o1_bf);

        launch_mfma<1,1>(stream, o1_bf, Wff1T + (long)i*512*128, Lff_b1 + (long)i*FF_,
                         ff1_bf, ROWS_, 512, 128, 0, 0, 0, 1);
        // ff2: s = o1 + ff2(ff1) (f32) + stats
        launch_mfma_stats(stream, ff1_bf, Wff2T + (long)i*128*512, Lff_b2 + i*E_,
                          sbuf, o1, sums2, ROWS_, 128, 512, 0, 0, 0, 1);

        bn_apply<<<2048, 256, 0, stream>>>(sbuf, sums2, Lbn2_g + i*E_, Lbn2_b + i*E_, x, x_bf);
    }

    // ---------------- decoder ----------------
    launch_mfma<1,0>(stream, x_bf, WdkvT, nullptr, dkv_bf, ROWS_, 256, 128, 0, 0, 0, 1);
    launch_mfma<0,0>(stream, x_bf, WshkT, nullptr, shk, N_, 128, 128, SPE, 0, (long)N_*E_, B_);
    qdec_kernel<<<B_, 128, 0, stream>>>(x, capacity, dWq, qdec_bf);

    attn_mfma2<1><<<ag, 256, 0, stream>>>(
        qdec_bf, 128, (long)G_*E_, G_,
        dkv_bf, 256, (long)P_*256, 0,
        ninf_mask, sols_mask_pomo, ocd_bf, (long)G_*E_);

    launch_mfma<0,0>(stream, ocd_bf, WmhdT, dcomb_b, mhd, B_*G_, 128, 128, 0, 0, 0, 1);

    dim3 sg(2, 2, B_);
    gemm_score<<<sg, 256, 0, stream>>>(mhd, shk, ninf_mask, scoreb,
                                       G_, N_, E_, (long)G_*E_, (long)N_*E_, (long)G_*N_);
    softmax_rows_kernel<<<(B_*G_)/4, 256, 0, stream>>>(scoreb, (float*)d_out);
}